// Round 11
// baseline (797.880 us; speedup 1.0000x reference)
//
#include <hip/hip_runtime.h>
#include <math.h>

#define NN 50000
#define NE 800000
// D = 128, H = 256

typedef __attribute__((ext_vector_type(8))) short s8_t;   // 8 bf16
typedef __attribute__((ext_vector_type(4))) float f4_t;   // 4 fp32

__device__ __forceinline__ short bf16_rne(float v) {
  unsigned u = __float_as_uint(v);
  unsigned r = (u + 0x7FFFu + ((u >> 16) & 1u)) >> 16;
  return (short)r;
}
__device__ __forceinline__ float bf16_tof(short h) {
  return __uint_as_float(((unsigned)(unsigned short)h) << 16);
}
__device__ __forceinline__ void split2(float v, short& hi, short& lo) {
  hi = bf16_rne(v);
  lo = bf16_rne(v - bf16_tof(hi));
}

// ---------------- weight split/transpose (W1, W2, W_in, W_out) ----------------

__global__ __launch_bounds__(256) void k_wcvt(const float* __restrict__ W1,
                                              const float* __restrict__ W2,
                                              const float* __restrict__ W_in,
                                              const float* __restrict__ W_out,
                                              short* __restrict__ w1th,
                                              short* __restrict__ w1tl,
                                              short* __restrict__ w2th,
                                              short* __restrict__ w2tl,
                                              short* __restrict__ winth,
                                              short* __restrict__ wintl,
                                              short* __restrict__ woutth,
                                              short* __restrict__ wouttl) {
  int i = blockIdx.x * 256 + threadIdx.x;
  if (i < 32768) {                    // W1 [256,128] -> [128][256]
    int k = i >> 7, n = i & 127;
    short h, l; split2(W1[i], h, l);
    w1th[n * 256 + k] = h; w1tl[n * 256 + k] = l;
  } else if (i < 49152) {             // W2 [128,128] -> [128][128]
    int j = i - 32768;
    int k = j >> 7, n = j & 127;
    short h, l; split2(W2[j], h, l);
    w2th[n * 128 + k] = h; w2tl[n * 128 + k] = l;
  } else if (i < 81920) {             // W_in [128,256] -> [256][128]
    int j = i - 49152;
    int k = j >> 8, n = j & 255;
    short h, l; split2(W_in[j], h, l);
    winth[n * 128 + k] = h; wintl[n * 128 + k] = l;
  } else if (i < 114688) {            // W_out [256,128] -> [128][256]
    int j = i - 81920;
    int k = j >> 7, n = j & 127;
    short h, l; split2(W_out[j], h, l);
    woutth[n * 256 + k] = h; wouttl[n * 256 + k] = l;
  }
}

// ---------------- CSR build: histogram ----------------

__global__ __launch_bounds__(256) void k_hist(const int* __restrict__ ei,
                                              const int* __restrict__ nei,
                                              const float* __restrict__ w,
                                              int* __restrict__ cnt1,
                                              float* __restrict__ deg1,
                                              int* __restrict__ cnt2) {
  int e = blockIdx.x * 256 + threadIdx.x;
  if (e < NE) {
    int c1 = ei[NE + e];
    atomicAdd(&cnt1[c1], 1);
    atomicAdd(&deg1[c1], w[e]);
    atomicAdd(&cnt2[nei[NE + e]], 1);
  }
}

// ---------------- hierarchical exclusive scan (+ dinv fused in part phase) ----

#define NCHUNK 196   // ceil(50000/256)

__global__ __launch_bounds__(256) void k_scan_part(const int* __restrict__ cnt1,
                                                   const int* __restrict__ cnt2,
                                                   const float* __restrict__ deg1,
                                                   float* __restrict__ dinv1,
                                                   float* __restrict__ dinv2,
                                                   int* __restrict__ part) {
  int g = blockIdx.x >= NCHUNK;
  int chunk = g ? blockIdx.x - NCHUNK : blockIdx.x;
  const int* cnt = g ? cnt2 : cnt1;
  int i = chunk * 256 + threadIdx.x;
  int v = (i < NN) ? cnt[i] : 0;
  if (i < NN) {
    if (!g) {
      float d1 = deg1[i];
      dinv1[i] = d1 > 0.f ? (1.0f / sqrtf(d1)) : 0.f;
    } else {
      dinv2[i] = v > 0 ? (1.0f / sqrtf((float)v)) : 0.f;
    }
  }
  __shared__ int sd[4];
  int r = v;
#pragma unroll
  for (int o = 32; o; o >>= 1) r += __shfl_down(r, o);
  if ((threadIdx.x & 63) == 0) sd[threadIdx.x >> 6] = r;
  __syncthreads();
  if (threadIdx.x == 0) part[blockIdx.x] = sd[0] + sd[1] + sd[2] + sd[3];
}

__global__ __launch_bounds__(256) void k_scan_mid(int* __restrict__ part,
                                                  int* __restrict__ off1_last,
                                                  int* __restrict__ off2_last) {
  __shared__ int sd[256];
  for (int g = 0; g < 2; g++) {
    int base = g * NCHUNK;
    int v = (threadIdx.x < NCHUNK) ? part[base + threadIdx.x] : 0;
    sd[threadIdx.x] = v;
    __syncthreads();
    for (int o = 1; o < 256; o <<= 1) {
      int x = (threadIdx.x >= o) ? sd[threadIdx.x - o] : 0;
      __syncthreads();
      sd[threadIdx.x] += x;
      __syncthreads();
    }
    if (threadIdx.x < NCHUNK) part[base + threadIdx.x] = sd[threadIdx.x] - v;
    if (threadIdx.x == 255) *(g ? off2_last : off1_last) = sd[255];
    __syncthreads();
  }
}

__global__ __launch_bounds__(256) void k_scan_final(const int* __restrict__ cnt1,
                                                    const int* __restrict__ cnt2,
                                                    const int* __restrict__ part,
                                                    int* __restrict__ off1,
                                                    int* __restrict__ pos1,
                                                    int* __restrict__ off2,
                                                    int* __restrict__ pos2) {
  int g = blockIdx.x >= NCHUNK;
  int chunk = g ? blockIdx.x - NCHUNK : blockIdx.x;
  const int* cnt = g ? cnt2 : cnt1;
  int* off = g ? off2 : off1;
  int* pos = g ? pos2 : pos1;
  __shared__ int sd[256];
  int i = chunk * 256 + threadIdx.x;
  int v = (i < NN) ? cnt[i] : 0;
  sd[threadIdx.x] = v;
  __syncthreads();
  for (int o = 1; o < 256; o <<= 1) {
    int x = (threadIdx.x >= o) ? sd[threadIdx.x - o] : 0;
    __syncthreads();
    sd[threadIdx.x] += x;
    __syncthreads();
  }
  if (i < NN) {
    int ex = part[blockIdx.x] + sd[threadIdx.x] - v;
    off[i] = ex; pos[i] = ex;
  }
}

// ---------------- fill CSR (packed records) ----------------

__global__ __launch_bounds__(256) void k_fill(const int* __restrict__ ei,
                                              const int* __restrict__ nei,
                                              const float* __restrict__ w,
                                              const float* __restrict__ dinv1,
                                              const float* __restrict__ dinv2,
                                              int* __restrict__ pos1,
                                              int4* __restrict__ c1pack,
                                              int* __restrict__ pos2,
                                              int2* __restrict__ c2pack) {
  int e = blockIdx.x * 256 + threadIdx.x;
  if (e < NE) {
    int r = ei[e], c = ei[NE + e];
    float nv = dinv1[r] * w[e] * dinv1[c];
    int s = atomicAdd(&pos1[c], 1);
    c1pack[s] = make_int4(r, c, e, __float_as_int(nv));
    int r2 = nei[e], c2v = nei[NE + e];
    float nv2 = dinv2[r2] * dinv2[c2v];
    int s2 = atomicAdd(&pos2[c2v], 1);
    c2pack[s2] = make_int2(r2, __float_as_int(nv2));
  }
}

// ---------------- fused layer1: aggregate (CSR) + MFMA GEMM1 + ELU ------------
// 32 nodes/block. Phase A: each wave aggregates 8 nodes (float4 half-wave)
// straight into the MFMA LDS layout (bf16 hi/lo). Phase B: x1 = elu(aggX@W_in+b).
// LDS 17.4 KB -> 8 blocks/CU (gather occupancy preserved).

__global__ __launch_bounds__(256) void k_l1a(const int* __restrict__ off,
                                             const int4* __restrict__ c1pack,
                                             const int* __restrict__ ids,
                                             const float* __restrict__ emb,
                                             const short* __restrict__ winth,
                                             const short* __restrict__ wintl,
                                             const float* __restrict__ b,
                                             short* __restrict__ x1h,
                                             short* __restrict__ x1l) {
  __shared__ short Xh[32 * 136];
  __shared__ short Xl[32 * 136];
  int t = threadIdx.x;
  int wave = t >> 6, lane = t & 63;
  int h = lane >> 5, sub = lane & 31;
  int n0 = blockIdx.x * 32;

  for (int kk = 0; kk < 8; kk++) {
    int row = wave * 8 + kk;
    int node = n0 + row;
    float4 acc = make_float4(0.f, 0.f, 0.f, 0.f);
    if (node < NN) {
      int start = off[node], end = off[node + 1];
      int i = start + h;
      for (; i + 14 < end; i += 16) {
        float4 v[8]; float n[8];
#pragma unroll
        for (int k = 0; k < 8; k++) {
          int4 p = c1pack[i + 2 * k];
          n[k] = __int_as_float(p.w);
          v[k] = *(const float4*)(emb + (size_t)ids[p.x] * 128 + sub * 4);
        }
#pragma unroll
        for (int k = 0; k < 8; k++) {
          acc.x = fmaf(n[k], v[k].x, acc.x);
          acc.y = fmaf(n[k], v[k].y, acc.y);
          acc.z = fmaf(n[k], v[k].z, acc.z);
          acc.w = fmaf(n[k], v[k].w, acc.w);
        }
      }
      for (; i < end; i += 2) {
        int4 p = c1pack[i];
        float n0v = __int_as_float(p.w);
        float4 v0 = *(const float4*)(emb + (size_t)ids[p.x] * 128 + sub * 4);
        acc.x = fmaf(n0v, v0.x, acc.x);
        acc.y = fmaf(n0v, v0.y, acc.y);
        acc.z = fmaf(n0v, v0.z, acc.z);
        acc.w = fmaf(n0v, v0.w, acc.w);
      }
    }
    acc.x += __shfl_xor(acc.x, 32);
    acc.y += __shfl_xor(acc.y, 32);
    acc.z += __shfl_xor(acc.z, 32);
    acc.w += __shfl_xor(acc.w, 32);
    if (h == 0) {
      uint2 hp = make_uint2(0u, 0u), lp = make_uint2(0u, 0u);
      if (node < NN) {
        short h0, l0, h1, l1, h2, l2, h3, l3;
        split2(acc.x, h0, l0); split2(acc.y, h1, l1);
        split2(acc.z, h2, l2); split2(acc.w, h3, l3);
        hp.x = (unsigned)(unsigned short)h0 | ((unsigned)(unsigned short)h1 << 16);
        hp.y = (unsigned)(unsigned short)h2 | ((unsigned)(unsigned short)h3 << 16);
        lp.x = (unsigned)(unsigned short)l0 | ((unsigned)(unsigned short)l1 << 16);
        lp.y = (unsigned)(unsigned short)l2 | ((unsigned)(unsigned short)l3 << 16);
      }
      *(uint2*)&Xh[row * 136 + sub * 4] = hp;
      *(uint2*)&Xl[row * 136 + sub * 4] = lp;
    }
  }
  __syncthreads();

  // ---- phase B: x1 = elu(aggX @ W_in + b), wave owns 64 cols ----
  int w = wave;
  int quad = lane >> 4, l16 = lane & 15;
  int nb = w * 64;
  int aoff0 = l16 * 136 + quad * 8;
  int aoff1 = (16 + l16) * 136 + quad * 8;

  f4_t acc[2][4];
#pragma unroll
  for (int mi = 0; mi < 2; mi++)
#pragma unroll
    for (int ni = 0; ni < 4; ni++) acc[mi][ni] = (f4_t){0.f, 0.f, 0.f, 0.f};

#pragma unroll
  for (int kb = 0; kb < 4; kb++) {
    int k0 = kb * 32;
    s8_t ah0 = *(const s8_t*)&Xh[aoff0 + k0];
    s8_t ah1 = *(const s8_t*)&Xh[aoff1 + k0];
    s8_t al0 = *(const s8_t*)&Xl[aoff0 + k0];
    s8_t al1 = *(const s8_t*)&Xl[aoff1 + k0];
#pragma unroll
    for (int ni = 0; ni < 4; ni++) {
      int bo = (nb + ni * 16 + l16) * 128 + quad * 8 + k0;
      s8_t bh = *(const s8_t*)(winth + bo);
      s8_t bl = *(const s8_t*)(wintl + bo);
      acc[0][ni] = __builtin_amdgcn_mfma_f32_16x16x32_bf16(ah0, bh, acc[0][ni], 0, 0, 0);
      acc[0][ni] = __builtin_amdgcn_mfma_f32_16x16x32_bf16(ah0, bl, acc[0][ni], 0, 0, 0);
      acc[0][ni] = __builtin_amdgcn_mfma_f32_16x16x32_bf16(al0, bh, acc[0][ni], 0, 0, 0);
      acc[1][ni] = __builtin_amdgcn_mfma_f32_16x16x32_bf16(ah1, bh, acc[1][ni], 0, 0, 0);
      acc[1][ni] = __builtin_amdgcn_mfma_f32_16x16x32_bf16(ah1, bl, acc[1][ni], 0, 0, 0);
      acc[1][ni] = __builtin_amdgcn_mfma_f32_16x16x32_bf16(al1, bh, acc[1][ni], 0, 0, 0);
    }
  }

#pragma unroll
  for (int mi = 0; mi < 2; mi++)
#pragma unroll
    for (int ni = 0; ni < 4; ni++) {
      int col = nb + ni * 16 + l16;
      float bv = b[col];
#pragma unroll
      for (int r = 0; r < 4; r++) {
        int node = n0 + mi * 16 + quad * 4 + r;
        if (node < NN) {
          float v = acc[mi][ni][r] + bv;
          v = v > 0.f ? v : expm1f(v);
          short hh, ll; split2(v, hh, ll);
          x1h[(size_t)node * 256 + col] = hh;
          x1l[(size_t)node * 256 + col] = ll;
        }
      }
    }
}

// ---------------- GEMM2 (MFMA): h2 = x1 @ W_out (fp32 out) ----------------

__global__ __launch_bounds__(256) void k_gemm2m(const short* __restrict__ x1h,
                                                const short* __restrict__ x1l,
                                                const short* __restrict__ woutth,
                                                const short* __restrict__ wouttl,
                                                float* __restrict__ h2) {
  __shared__ short Xh[32 * 264];
  __shared__ short Xl[32 * 264];
  int t = threadIdx.x;
  int n0 = blockIdx.x * 32;
#pragma unroll
  for (int j = 0; j < 4; j++) {
    int i = t + 256 * j;
    int row = i >> 5, q = i & 31;
    int node = n0 + row; if (node >= NN) node = NN - 1;
    *(uint4*)&Xh[row * 264 + q * 8] = *(const uint4*)(x1h + (size_t)node * 256 + q * 8);
    *(uint4*)&Xl[row * 264 + q * 8] = *(const uint4*)(x1l + (size_t)node * 256 + q * 8);
  }
  __syncthreads();

  int w = t >> 6, lane = t & 63;
  int quad = lane >> 4, l16 = lane & 15;
  int nb = w * 32;
  int aoff0 = l16 * 264 + quad * 8;
  int aoff1 = (16 + l16) * 264 + quad * 8;

  f4_t acc[2][2];
#pragma unroll
  for (int mi = 0; mi < 2; mi++)
#pragma unroll
    for (int ni = 0; ni < 2; ni++) acc[mi][ni] = (f4_t){0.f, 0.f, 0.f, 0.f};

#pragma unroll
  for (int kb = 0; kb < 8; kb++) {
    int k0 = kb * 32;
    s8_t ah0 = *(const s8_t*)&Xh[aoff0 + k0];
    s8_t ah1 = *(const s8_t*)&Xh[aoff1 + k0];
    s8_t al0 = *(const s8_t*)&Xl[aoff0 + k0];
    s8_t al1 = *(const s8_t*)&Xl[aoff1 + k0];
#pragma unroll
    for (int ni = 0; ni < 2; ni++) {
      int bo = (nb + ni * 16 + l16) * 256 + quad * 8 + k0;
      s8_t bh = *(const s8_t*)(woutth + bo);
      s8_t bl = *(const s8_t*)(wouttl + bo);
      acc[0][ni] = __builtin_amdgcn_mfma_f32_16x16x32_bf16(ah0, bh, acc[0][ni], 0, 0, 0);
      acc[0][ni] = __builtin_amdgcn_mfma_f32_16x16x32_bf16(ah0, bl, acc[0][ni], 0, 0, 0);
      acc[0][ni] = __builtin_amdgcn_mfma_f32_16x16x32_bf16(al0, bh, acc[0][ni], 0, 0, 0);
      acc[1][ni] = __builtin_amdgcn_mfma_f32_16x16x32_bf16(ah1, bh, acc[1][ni], 0, 0, 0);
      acc[1][ni] = __builtin_amdgcn_mfma_f32_16x16x32_bf16(ah1, bl, acc[1][ni], 0, 0, 0);
      acc[1][ni] = __builtin_amdgcn_mfma_f32_16x16x32_bf16(al1, bh, acc[1][ni], 0, 0, 0);
    }
  }

#pragma unroll
  for (int mi = 0; mi < 2; mi++)
#pragma unroll
    for (int ni = 0; ni < 2; ni++) {
      int col = nb + ni * 16 + l16;
#pragma unroll
      for (int r = 0; r < 4; r++) {
        int node = n0 + mi * 16 + quad * 4 + r;
        if (node < NN) h2[(size_t)node * 128 + col] = acc[mi][ni][r];
      }
    }
}

// ---------------- fused layer2+pab: aggregate h2 + ELU + double MFMA ----------
// 32 nodes/block. Phase A: wave aggregates 8 nodes from h2 (CSR graph 2),
// bias+ELU+bf16-split into MFMA LDS layout. Phase B: Pa/Pb GEMMs (b1 folded).

__global__ __launch_bounds__(256) void k_l2b(const int* __restrict__ off,
                                             const int2* __restrict__ c2pack,
                                             const float* __restrict__ h2,
                                             const float* __restrict__ b,
                                             const short* __restrict__ w1th,
                                             const short* __restrict__ w1tl,
                                             const float* __restrict__ b1,
                                             float* __restrict__ Pa,
                                             float* __restrict__ Pb) {
  __shared__ short Xh[32 * 136];
  __shared__ short Xl[32 * 136];
  int t = threadIdx.x;
  int wave = t >> 6, lane = t & 63;
  int h = lane >> 5, sub = lane & 31;
  int n0 = blockIdx.x * 32;

  for (int kk = 0; kk < 8; kk++) {
    int row = wave * 8 + kk;
    int node = n0 + row;
    float4 acc = make_float4(0.f, 0.f, 0.f, 0.f);
    if (node < NN) {
      int start = off[node], end = off[node + 1];
      int i = start + h;
      for (; i + 14 < end; i += 16) {
        float4 v[8]; float n[8];
#pragma unroll
        for (int k = 0; k < 8; k++) {
          int2 p = c2pack[i + 2 * k];
          n[k] = __int_as_float(p.y);
          v[k] = *(const float4*)(h2 + (size_t)p.x * 128 + sub * 4);
        }
#pragma unroll
        for (int k = 0; k < 8; k++) {
          acc.x = fmaf(n[k], v[k].x, acc.x);
          acc.y = fmaf(n[k], v[k].y, acc.y);
          acc.z = fmaf(n[k], v[k].z, acc.z);
          acc.w = fmaf(n[k], v[k].w, acc.w);
        }
      }
      for (; i < end; i += 2) {
        int2 p = c2pack[i];
        float n0v = __int_as_float(p.y);
        float4 v0 = *(const float4*)(h2 + (size_t)p.x * 128 + sub * 4);
        acc.x = fmaf(n0v, v0.x, acc.x);
        acc.y = fmaf(n0v, v0.y, acc.y);
        acc.z = fmaf(n0v, v0.z, acc.z);
        acc.w = fmaf(n0v, v0.w, acc.w);
      }
    }
    acc.x += __shfl_xor(acc.x, 32);
    acc.y += __shfl_xor(acc.y, 32);
    acc.z += __shfl_xor(acc.z, 32);
    acc.w += __shfl_xor(acc.w, 32);
    if (h == 0) {
      uint2 hp = make_uint2(0u, 0u), lp = make_uint2(0u, 0u);
      if (node < NN) {
        float4 bb = *(const float4*)(b + sub * 4);
        float v0 = acc.x + bb.x, v1 = acc.y + bb.y;
        float v2 = acc.z + bb.z, v3 = acc.w + bb.w;
        v0 = v0 > 0.f ? v0 : expm1f(v0);
        v1 = v1 > 0.f ? v1 : expm1f(v1);
        v2 = v2 > 0.f ? v2 : expm1f(v2);
        v3 = v3 > 0.f ? v3 : expm1f(v3);
        short h0, l0, h1, l1, h2s, l2, h3, l3;
        split2(v0, h0, l0); split2(v1, h1, l1);
        split2(v2, h2s, l2); split2(v3, h3, l3);
        hp.x = (unsigned)(unsigned short)h0 | ((unsigned)(unsigned short)h1 << 16);
        hp.y = (unsigned)(unsigned short)h2s | ((unsigned)(unsigned short)h3 << 16);
        lp.x = (unsigned)(unsigned short)l0 | ((unsigned)(unsigned short)l1 << 16);
        lp.y = (unsigned)(unsigned short)l2 | ((unsigned)(unsigned short)l3 << 16);
      }
      *(uint2*)&Xh[row * 136 + sub * 4] = hp;
      *(uint2*)&Xl[row * 136 + sub * 4] = lp;
    }
  }
  __syncthreads();

  // ---- phase B: Pa = x2@W1[:128], Pb = x2@W1[128:] + b1 ----
  int w = wave;
  int quad = lane >> 4, l16 = lane & 15;
  int nb = w * 32;
  int aoff0 = l16 * 136 + quad * 8;
  int aoff1 = (16 + l16) * 136 + quad * 8;
  int bo0 = (nb + l16) * 256 + quad * 8;
  int bo1 = (nb + 16 + l16) * 256 + quad * 8;

  f4_t aa[2][2], ab[2][2];
#pragma unroll
  for (int mi = 0; mi < 2; mi++)
#pragma unroll
    for (int ni = 0; ni < 2; ni++) {
      aa[mi][ni] = (f4_t){0.f, 0.f, 0.f, 0.f};
      ab[mi][ni] = (f4_t){0.f, 0.f, 0.f, 0.f};
    }

#pragma unroll
  for (int kb = 0; kb < 4; kb++) {
    int k0 = kb * 32;
    s8_t ah0 = *(const s8_t*)&Xh[aoff0 + k0];
    s8_t ah1 = *(const s8_t*)&Xh[aoff1 + k0];
    s8_t al0 = *(const s8_t*)&Xl[aoff0 + k0];
    s8_t al1 = *(const s8_t*)&Xl[aoff1 + k0];
    {
      s8_t bh0 = *(const s8_t*)(w1th + bo0 + k0);
      s8_t bh1 = *(const s8_t*)(w1th + bo1 + k0);
      s8_t bl0 = *(const s8_t*)(w1tl + bo0 + k0);
      s8_t bl1 = *(const s8_t*)(w1tl + bo1 + k0);
      aa[0][0] = __builtin_amdgcn_mfma_f32_16x16x32_bf16(ah0, bh0, aa[0][0], 0, 0, 0);
      aa[0][0] = __builtin_amdgcn_mfma_f32_16x16x32_bf16(ah0, bl0, aa[0][0], 0, 0, 0);
      aa[0][0] = __builtin_amdgcn_mfma_f32_16x16x32_bf16(al0, bh0, aa[0][0], 0, 0, 0);
      aa[0][1] = __builtin_amdgcn_mfma_f32_16x16x32_bf16(ah0, bh1, aa[0][1], 0, 0, 0);
      aa[0][1] = __builtin_amdgcn_mfma_f32_16x16x32_bf16(ah0, bl1, aa[0][1], 0, 0, 0);
      aa[0][1] = __builtin_amdgcn_mfma_f32_16x16x32_bf16(al0, bh1, aa[0][1], 0, 0, 0);
      aa[1][0] = __builtin_amdgcn_mfma_f32_16x16x32_bf16(ah1, bh0, aa[1][0], 0, 0, 0);
      aa[1][0] = __builtin_amdgcn_mfma_f32_16x16x32_bf16(ah1, bl0, aa[1][0], 0, 0, 0);
      aa[1][0] = __builtin_amdgcn_mfma_f32_16x16x32_bf16(al1, bh0, aa[1][0], 0, 0, 0);
      aa[1][1] = __builtin_amdgcn_mfma_f32_16x16x32_bf16(ah1, bh1, aa[1][1], 0, 0, 0);
      aa[1][1] = __builtin_amdgcn_mfma_f32_16x16x32_bf16(ah1, bl1, aa[1][1], 0, 0, 0);
      aa[1][1] = __builtin_amdgcn_mfma_f32_16x16x32_bf16(al1, bh1, aa[1][1], 0, 0, 0);
    }
    {
      s8_t bh0 = *(const s8_t*)(w1th + bo0 + 128 + k0);
      s8_t bh1 = *(const s8_t*)(w1th + bo1 + 128 + k0);
      s8_t bl0 = *(const s8_t*)(w1tl + bo0 + 128 + k0);
      s8_t bl1 = *(const s8_t*)(w1tl + bo1 + 128 + k0);
      ab[0][0] = __builtin_amdgcn_mfma_f32_16x16x32_bf16(ah0, bh0, ab[0][0], 0, 0, 0);
      ab[0][0] = __builtin_amdgcn_mfma_f32_16x16x32_bf16(ah0, bl0, ab[0][0], 0, 0, 0);
      ab[0][0] = __builtin_amdgcn_mfma_f32_16x16x32_bf16(al0, bh0, ab[0][0], 0, 0, 0);
      ab[0][1] = __builtin_amdgcn_mfma_f32_16x16x32_bf16(ah0, bh1, ab[0][1], 0, 0, 0);
      ab[0][1] = __builtin_amdgcn_mfma_f32_16x16x32_bf16(ah0, bl1, ab[0][1], 0, 0, 0);
      ab[0][1] = __builtin_amdgcn_mfma_f32_16x16x32_bf16(al0, bh1, ab[0][1], 0, 0, 0);
      ab[1][0] = __builtin_amdgcn_mfma_f32_16x16x32_bf16(ah1, bh0, ab[1][0], 0, 0, 0);
      ab[1][0] = __builtin_amdgcn_mfma_f32_16x16x32_bf16(ah1, bl0, ab[1][0], 0, 0, 0);
      ab[1][0] = __builtin_amdgcn_mfma_f32_16x16x32_bf16(al1, bh0, ab[1][0], 0, 0, 0);
      ab[1][1] = __builtin_amdgcn_mfma_f32_16x16x32_bf16(ah1, bh1, ab[1][1], 0, 0, 0);
      ab[1][1] = __builtin_amdgcn_mfma_f32_16x16x32_bf16(ah1, bl1, ab[1][1], 0, 0, 0);
      ab[1][1] = __builtin_amdgcn_mfma_f32_16x16x32_bf16(al1, bh1, ab[1][1], 0, 0, 0);
    }
  }

  float b1v0 = b1[nb + l16], b1v1 = b1[nb + 16 + l16];
#pragma unroll
  for (int mi = 0; mi < 2; mi++)
#pragma unroll
    for (int ni = 0; ni < 2; ni++) {
      int col = nb + ni * 16 + l16;
      float bv = ni ? b1v1 : b1v0;
#pragma unroll
      for (int r = 0; r < 4; r++) {
        int node = n0 + mi * 16 + quad * 4 + r;
        if (node < NN) {
          Pa[(size_t)node * 128 + col] = aa[mi][ni][r];
          Pb[(size_t)node * 128 + col] = ab[mi][ni][r] + bv;
        }
      }
    }
}

// ---------------- fused edge decoder v9 (batched t1 loads) ----------------

#define ST 136   // t1 LDS stride (shorts)

__global__ __launch_bounds__(256, 4) void k_decoder(
    const float* __restrict__ Pa, const float* __restrict__ Pb,
    const int4* __restrict__ c1pack,
    const short* __restrict__ w2th, const short* __restrict__ w2tl,
    const float* __restrict__ b2,
    const float* __restrict__ W3, const float* __restrict__ b3,
    float* __restrict__ out) {
  __shared__ short Th[32 * ST];
  __shared__ short Tl[32 * ST];
  __shared__ float part[4][32];

  int t = threadIdx.x;
  int b = blockIdx.x;
  int id = (b & 7) * 3125 + (b >> 3);   // XCD-contiguous CSR ranges
  int s0base = id * 32;

  // ---- t1 stage: all 8 float4 gathers issued before any use ----
  {
    int le0 = t >> 4, q = t & 15;
    int4 p0 = c1pack[s0base + le0];
    int4 p1 = c1pack[s0base + le0 + 16];
    const float* pa0 = Pa + (size_t)p0.x * 128 + q * 8;
    const float* pb0 = Pb + (size_t)p0.y * 128 + q * 8;
    const float* pa1 = Pa + (size_t)p1.x * 128 + q * 8;
    const float* pb1 = Pb + (size_t)p1.y * 128 + q * 8;
    float4 ra0 = *(const float4*)(pa0);
    float4 ra1 = *(const float4*)(pa0 + 4);
    float4 rb0 = *(const float4*)(pb0);
    float4 rb1 = *(const float4*)(pb0 + 4);
    float4 ra2 = *(const float4*)(pa1);
    float4 ra3 = *(const float4*)(pa1 + 4);
    float4 rb2 = *(const float4*)(pb1);
    float4 rb3 = *(const float4*)(pb1 + 4);

    float v0[8], v1[8];
    v0[0] = ra0.x + rb0.x; v0[1] = ra0.y + rb0.y;
    v0[2] = ra0.z + rb0.z; v0[3] = ra0.w + rb0.w;
    v0[4] = ra1.x + rb1.x; v0[5] = ra1.y + rb1.y;
    v0[6] = ra1.z + rb1.z; v0[7] = ra1.w + rb1.w;
    v1[0] = ra2.x + rb2.x; v1[1] = ra2.y + rb2.y;
    v1[2] = ra2.z + rb2.z; v1[3] = ra2.w + rb2.w;
    v1[4] = ra3.x + rb3.x; v1[5] = ra3.y + rb3.y;
    v1[6] = ra3.z + rb3.z; v1[7] = ra3.w + rb3.w;

    s8_t hv0, lv0, hv1, lv1;
#pragma unroll
    for (int k = 0; k < 8; k++) {
      float x0 = fmaxf(v0[k], 0.f);
      float x1 = fmaxf(v1[k], 0.f);
      short hh, ll;
      split2(x0, hh, ll); hv0[k] = hh; lv0[k] = ll;
      split2(x1, hh, ll); hv1[k] = hh; lv1[k] = ll;
    }
    *(s8_t*)&Th[le0 * ST + q * 8] = hv0;
    *(s8_t*)&Tl[le0 * ST + q * 8] = lv0;
    *(s8_t*)&Th[(le0 + 16) * ST + q * 8] = hv1;
    *(s8_t*)&Tl[(le0 + 16) * ST + q * 8] = lv1;
  }
  __syncthreads();

  int w = t >> 6, lane = t & 63;
  int quad = lane >> 4, l16 = lane & 15;
  int nb = w * 32;
  float b2v0 = b2[nb + l16], b2v1 = b2[nb + 16 + l16];
  float w3a = W3[nb + l16], w3b = W3[nb + 16 + l16];

  int toff0 = l16 * ST + quad * 8;
  int toff1 = (16 + l16) * ST + quad * 8;
  int coff0 = (nb + l16) * 128 + quad * 8;
  int coff1 = (nb + 16 + l16) * 128 + quad * 8;

  f4_t acc2[2][2];
#pragma unroll
  for (int mi = 0; mi < 2; mi++)
#pragma unroll
    for (int ni = 0; ni < 2; ni++) acc2[mi][ni] = (f4_t){0.f, 0.f, 0.f, 0.f};

#pragma unroll
  for (int kb = 0; kb < 4; kb++) {
    int k0 = kb * 32;
    s8_t ah0 = *(const s8_t*)&Th[toff0 + k0];
    s8_t ah1 = *(const s8_t*)&Th[toff1 + k0];
    s8_t al0 = *(const s8_t*)&Tl[toff0 + k0];
    s8_t al1 = *(const s8_t*)&Tl[toff1 + k0];
    s8_t bh0 = *(const s8_t*)(w2th + coff0 + k0);
    s8_t bh1 = *(const s8_t*)(w2th + coff1 + k0);
    s8_t bl0 = *(const s8_t*)(w2tl + coff0 + k0);
    s8_t bl1 = *(const s8_t*)(w2tl + coff1 + k0);
    acc2[0][0] = __builtin_amdgcn_mfma_f32_16x16x32_bf16(ah0, bh0, acc2[0][0], 0, 0, 0);
    acc2[0][0] = __builtin_amdgcn_mfma_f32_16x16x32_bf16(ah0, bl0, acc2[0][0], 0, 0, 0);
    acc2[0][0] = __builtin_amdgcn_mfma_f32_16x16x32_bf16(al0, bh0, acc2[0][0], 0, 0, 0);
    acc2[0][1] = __builtin_amdgcn_mfma_f32_16x16x32_bf16(ah0, bh1, acc2[0][1], 0, 0, 0);
    acc2[0][1] = __builtin_amdgcn_mfma_f32_16x16x32_bf16(ah0, bl1, acc2[0][1], 0, 0, 0);
    acc2[0][1] = __builtin_amdgcn_mfma_f32_16x16x32_bf16(al0, bh1, acc2[0][1], 0, 0, 0);
    acc2[1][0] = __builtin_amdgcn_mfma_f32_16x16x32_bf16(ah1, bh0, acc2[1][0], 0, 0, 0);
    acc2[1][0] = __builtin_amdgcn_mfma_f32_16x16x32_bf16(ah1, bl0, acc2[1][0], 0, 0, 0);
    acc2[1][0] = __builtin_amdgcn_mfma_f32_16x16x32_bf16(al1, bh0, acc2[1][0], 0, 0, 0);
    acc2[1][1] = __builtin_amdgcn_mfma_f32_16x16x32_bf16(ah1, bh1, acc2[1][1], 0, 0, 0);
    acc2[1][1] = __builtin_amdgcn_mfma_f32_16x16x32_bf16(ah1, bl1, acc2[1][1], 0, 0, 0);
    acc2[1][1] = __builtin_amdgcn_mfma_f32_16x16x32_bf16(al1, bh1, acc2[1][1], 0, 0, 0);
  }

#pragma unroll
  for (int mi = 0; mi < 2; mi++) {
#pragma unroll
    for (int r = 0; r < 4; r++) {
      float pv = fmaxf(acc2[mi][0][r] + b2v0, 0.f) * w3a +
                 fmaxf(acc2[mi][1][r] + b2v1, 0.f) * w3b;
      pv += __shfl_xor(pv, 1);
      pv += __shfl_xor(pv, 2);
      pv += __shfl_xor(pv, 4);
      pv += __shfl_xor(pv, 8);
      if (l16 == 0) part[w][mi * 16 + quad * 4 + r] = pv;
    }
  }
  __syncthreads();

  if (t < 32) {
    float s = part[0][t] + part[1][t] + part[2][t] + part[3][t] + b3[0];
    int4 p = c1pack[s0base + t];
    out[p.z] = s;
  }
}

// ---------------- launch ----------------

extern "C" void kernel_launch(void* const* d_in, const int* in_sizes, int n_in,
                              void* d_out, int out_size, void* d_ws, size_t ws_size,
                              hipStream_t stream) {
  const int*   node_ids = (const int*)d_in[0];
  const int*   ei       = (const int*)d_in[1];
  const int*   nei      = (const int*)d_in[2];
  const float* eattr    = (const float*)d_in[3];
  const float* emb      = (const float*)d_in[4];
  const float* W_in     = (const float*)d_in[5];
  const float* b_in     = (const float*)d_in[6];
  const float* W_out    = (const float*)d_in[7];
  const float* b_out    = (const float*)d_in[8];
  const float* W1       = (const float*)d_in[9];
  const float* b1       = (const float*)d_in[10];
  const float* W2       = (const float*)d_in[11];
  const float* b2       = (const float*)d_in[12];
  const float* W3       = (const float*)d_in[13];
  const float* b3       = (const float*)d_in[14];
  float* out = (float*)d_out;

  // workspace layout (floats)
  float* ws    = (float*)d_ws;
  float* bufA  = ws;                          // N*128 f: h2
  float* bufB  = bufA + (size_t)NN * 128;     // N*256 f: x1h/l -> Pa|Pb
  int*   cnt1  = (int*)(bufB + (size_t)NN * 256);
  int*   cnt2  = cnt1 + NN;
  float* deg1  = (float*)(cnt2 + NN);
  float* dinv1 = deg1 + NN;
  float* dinv2 = dinv1 + NN;
  int*   off1  = (int*)(dinv2 + NN);          // N+1
  int*   pos1  = off1 + NN + 1;               // N
  int*   off2  = pos1 + NN;                   // N+1
  int*   pos2  = off2 + NN + 1;               // N
  int4*  c1pack = (int4*)((((uintptr_t)(pos2 + NN)) + 15) & ~(uintptr_t)15);  // E
  int2*  c2pack = (int2*)(c1pack + NE);                                       // E
  short* w1th   = (short*)(c2pack + NE);
  short* w1tl   = w1th + 32768;
  short* w2th   = w1tl + 32768;
  short* w2tl   = w2th + 16384;
  short* winth  = w2tl + 16384;
  short* wintl  = winth + 32768;
  short* woutth = wintl + 32768;
  short* wouttl = woutth + 32768;
  int*   part   = (int*)(wouttl + 32768);     // 2*NCHUNK

  float* h2    = bufA;
  short* x1h   = (short*)bufB;                // N*256 shorts
  short* x1l   = x1h + (size_t)NN * 256;
  float* Pa    = bufB;                        // overwrites x1 (dead after gemm2m)
  float* Pb    = bufB + (size_t)NN * 128;

  // weight split (W1, W2, W_in^T, W_out^T)
  k_wcvt<<<448, 256, 0, stream>>>(W1, W2, W_in, W_out,
                                  w1th, w1tl, w2th, w2tl,
                                  winth, wintl, woutth, wouttl);

  // CSR build: hist -> scan(3-phase, dinv fused) -> fill
  hipMemsetAsync(cnt1, 0, 3 * (size_t)NN * sizeof(int), stream);  // cnt1,cnt2,deg1
  k_hist<<<NE / 256, 256, 0, stream>>>(ei, nei, eattr, cnt1, deg1, cnt2);
  k_scan_part<<<2 * NCHUNK, 256, 0, stream>>>(cnt1, cnt2, deg1, dinv1, dinv2, part);
  k_scan_mid<<<1, 256, 0, stream>>>(part, off1 + NN, off2 + NN);
  k_scan_final<<<2 * NCHUNK, 256, 0, stream>>>(cnt1, cnt2, part,
                                               off1, pos1, off2, pos2);
  k_fill<<<NE / 256, 256, 0, stream>>>(ei, nei, eattr, dinv1, dinv2,
                                       pos1, c1pack, pos2, c2pack);

  // layer 1 fused: aggregate + GEMM1 + ELU -> x1 (bf16 hi/lo)
  k_l1a<<<(NN + 31) / 32, 256, 0, stream>>>(off1, c1pack, node_ids, emb,
                                            winth, wintl, b_in, x1h, x1l);

  // layer 2a: h2 = x1 @ W_out (MFMA)
  k_gemm2m<<<(NN + 31) / 32, 256, 0, stream>>>(x1h, x1l, woutth, wouttl, h2);

  // layer 2b fused: aggregate h2 + bias + ELU + Pa/Pb GEMMs (b1 folded)
  k_l2b<<<(NN + 31) / 32, 256, 0, stream>>>(off2, c2pack, h2, b_out,
                                            w1th, w1tl, b1, Pa, Pb);

  // decoder v9 (batched t1 gathers)
  k_decoder<<<NE / 32, 256, 0, stream>>>(Pa, Pb, c1pack,
                                         w2th, w2tl, b2, W3, b3, out);
}

// Round 12
// 730.221 us; speedup vs baseline: 1.0927x; 1.0927x over previous
//
#include <hip/hip_runtime.h>
#include <math.h>

#define NN 50000
#define NE 800000
// D = 128, H = 256

typedef __attribute__((ext_vector_type(8))) short s8_t;   // 8 bf16
typedef __attribute__((ext_vector_type(4))) float f4_t;   // 4 fp32

__device__ __forceinline__ short bf16_rne(float v) {
  unsigned u = __float_as_uint(v);
  unsigned r = (u + 0x7FFFu + ((u >> 16) & 1u)) >> 16;
  return (short)r;
}
__device__ __forceinline__ float bf16_tof(short h) {
  return __uint_as_float(((unsigned)(unsigned short)h) << 16);
}
__device__ __forceinline__ void split2(float v, short& hi, short& lo) {
  hi = bf16_rne(v);
  lo = bf16_rne(v - bf16_tof(hi));
}

// ---------------- weight split/transpose (W1, W2, W_in, W_out) ----------------

__global__ __launch_bounds__(256) void k_wcvt(const float* __restrict__ W1,
                                              const float* __restrict__ W2,
                                              const float* __restrict__ W_in,
                                              const float* __restrict__ W_out,
                                              short* __restrict__ w1th,
                                              short* __restrict__ w1tl,
                                              short* __restrict__ w2th,
                                              short* __restrict__ w2tl,
                                              short* __restrict__ winth,
                                              short* __restrict__ wintl,
                                              short* __restrict__ woutth,
                                              short* __restrict__ wouttl) {
  int i = blockIdx.x * 256 + threadIdx.x;
  if (i < 32768) {                    // W1 [256,128] -> [128][256]
    int k = i >> 7, n = i & 127;
    short h, l; split2(W1[i], h, l);
    w1th[n * 256 + k] = h; w1tl[n * 256 + k] = l;
  } else if (i < 49152) {             // W2 [128,128] -> [128][128]
    int j = i - 32768;
    int k = j >> 7, n = j & 127;
    short h, l; split2(W2[j], h, l);
    w2th[n * 128 + k] = h; w2tl[n * 128 + k] = l;
  } else if (i < 81920) {             // W_in [128,256] -> [256][128]
    int j = i - 49152;
    int k = j >> 8, n = j & 255;
    short h, l; split2(W_in[j], h, l);
    winth[n * 128 + k] = h; wintl[n * 128 + k] = l;
  } else if (i < 114688) {            // W_out [256,128] -> [128][256]
    int j = i - 81920;
    int k = j >> 7, n = j & 127;
    short h, l; split2(W_out[j], h, l);
    woutth[n * 256 + k] = h; wouttl[n * 256 + k] = l;
  }
}

// ---------------- CSR build: histogram ----------------

__global__ __launch_bounds__(256) void k_hist(const int* __restrict__ ei,
                                              const int* __restrict__ nei,
                                              const float* __restrict__ w,
                                              int* __restrict__ cnt1,
                                              float* __restrict__ deg1,
                                              int* __restrict__ cnt2) {
  int e = blockIdx.x * 256 + threadIdx.x;
  if (e < NE) {
    int c1 = ei[NE + e];
    atomicAdd(&cnt1[c1], 1);
    atomicAdd(&deg1[c1], w[e]);
    atomicAdd(&cnt2[nei[NE + e]], 1);
  }
}

// ---------------- hierarchical exclusive scan (+ dinv fused in part phase) ----

#define NCHUNK 196   // ceil(50000/256)

__global__ __launch_bounds__(256) void k_scan_part(const int* __restrict__ cnt1,
                                                   const int* __restrict__ cnt2,
                                                   const float* __restrict__ deg1,
                                                   float* __restrict__ dinv1,
                                                   float* __restrict__ dinv2,
                                                   int* __restrict__ part) {
  int g = blockIdx.x >= NCHUNK;
  int chunk = g ? blockIdx.x - NCHUNK : blockIdx.x;
  const int* cnt = g ? cnt2 : cnt1;
  int i = chunk * 256 + threadIdx.x;
  int v = (i < NN) ? cnt[i] : 0;
  if (i < NN) {
    if (!g) {
      float d1 = deg1[i];
      dinv1[i] = d1 > 0.f ? (1.0f / sqrtf(d1)) : 0.f;
    } else {
      dinv2[i] = v > 0 ? (1.0f / sqrtf((float)v)) : 0.f;
    }
  }
  __shared__ int sd[4];
  int r = v;
#pragma unroll
  for (int o = 32; o; o >>= 1) r += __shfl_down(r, o);
  if ((threadIdx.x & 63) == 0) sd[threadIdx.x >> 6] = r;
  __syncthreads();
  if (threadIdx.x == 0) part[blockIdx.x] = sd[0] + sd[1] + sd[2] + sd[3];
}

__global__ __launch_bounds__(256) void k_scan_mid(int* __restrict__ part,
                                                  int* __restrict__ off1_last,
                                                  int* __restrict__ off2_last) {
  __shared__ int sd[256];
  for (int g = 0; g < 2; g++) {
    int base = g * NCHUNK;
    int v = (threadIdx.x < NCHUNK) ? part[base + threadIdx.x] : 0;
    sd[threadIdx.x] = v;
    __syncthreads();
    for (int o = 1; o < 256; o <<= 1) {
      int x = (threadIdx.x >= o) ? sd[threadIdx.x - o] : 0;
      __syncthreads();
      sd[threadIdx.x] += x;
      __syncthreads();
    }
    if (threadIdx.x < NCHUNK) part[base + threadIdx.x] = sd[threadIdx.x] - v;
    if (threadIdx.x == 255) *(g ? off2_last : off1_last) = sd[255];
    __syncthreads();
  }
}

__global__ __launch_bounds__(256) void k_scan_final(const int* __restrict__ cnt1,
                                                    const int* __restrict__ cnt2,
                                                    const int* __restrict__ part,
                                                    int* __restrict__ off1,
                                                    int* __restrict__ pos1,
                                                    int* __restrict__ off2,
                                                    int* __restrict__ pos2) {
  int g = blockIdx.x >= NCHUNK;
  int chunk = g ? blockIdx.x - NCHUNK : blockIdx.x;
  const int* cnt = g ? cnt2 : cnt1;
  int* off = g ? off2 : off1;
  int* pos = g ? pos2 : pos1;
  __shared__ int sd[256];
  int i = chunk * 256 + threadIdx.x;
  int v = (i < NN) ? cnt[i] : 0;
  sd[threadIdx.x] = v;
  __syncthreads();
  for (int o = 1; o < 256; o <<= 1) {
    int x = (threadIdx.x >= o) ? sd[threadIdx.x - o] : 0;
    __syncthreads();
    sd[threadIdx.x] += x;
    __syncthreads();
  }
  if (i < NN) {
    int ex = part[blockIdx.x] + sd[threadIdx.x] - v;
    off[i] = ex; pos[i] = ex;
  }
}

// ---------------- fill CSR (packed records) ----------------

__global__ __launch_bounds__(256) void k_fill(const int* __restrict__ ei,
                                              const int* __restrict__ nei,
                                              const float* __restrict__ w,
                                              const float* __restrict__ dinv1,
                                              const float* __restrict__ dinv2,
                                              int* __restrict__ pos1,
                                              int4* __restrict__ c1pack,
                                              int* __restrict__ pos2,
                                              int2* __restrict__ c2pack) {
  int e = blockIdx.x * 256 + threadIdx.x;
  if (e < NE) {
    int r = ei[e], c = ei[NE + e];
    float nv = dinv1[r] * w[e] * dinv1[c];
    int s = atomicAdd(&pos1[c], 1);
    c1pack[s] = make_int4(r, c, e, __float_as_int(nv));
    int r2 = nei[e], c2v = nei[NE + e];
    float nv2 = dinv2[r2] * dinv2[c2v];
    int s2 = atomicAdd(&pos2[c2v], 1);
    c2pack[s2] = make_int2(r2, __float_as_int(nv2));
  }
}

// ---------------- layer1 aggregate: float4 half-wave, bf16-split output -------
// (round-10 measured-good version: one wave per node, 12500 blocks)

__global__ __launch_bounds__(256) void k_agg1(const int* __restrict__ off,
                                              const int4* __restrict__ c1pack,
                                              const int* __restrict__ ids,
                                              const float* __restrict__ emb,
                                              short* __restrict__ aggXh,
                                              short* __restrict__ aggXl) {
  int wave = threadIdx.x >> 6, lane = threadIdx.x & 63;
  int h = lane >> 5, sub = lane & 31;
  int node = blockIdx.x * 4 + wave;
  int start = off[node], end = off[node + 1];
  float4 acc = make_float4(0.f, 0.f, 0.f, 0.f);
  int i = start + h;
  for (; i + 14 < end; i += 16) {
    float4 v[8]; float n[8];
#pragma unroll
    for (int k = 0; k < 8; k++) {
      int4 p = c1pack[i + 2 * k];
      n[k] = __int_as_float(p.w);
      v[k] = *(const float4*)(emb + (size_t)ids[p.x] * 128 + sub * 4);
    }
#pragma unroll
    for (int k = 0; k < 8; k++) {
      acc.x = fmaf(n[k], v[k].x, acc.x);
      acc.y = fmaf(n[k], v[k].y, acc.y);
      acc.z = fmaf(n[k], v[k].z, acc.z);
      acc.w = fmaf(n[k], v[k].w, acc.w);
    }
  }
  for (; i < end; i += 2) {
    int4 p = c1pack[i];
    float n0 = __int_as_float(p.w);
    float4 v0 = *(const float4*)(emb + (size_t)ids[p.x] * 128 + sub * 4);
    acc.x = fmaf(n0, v0.x, acc.x);
    acc.y = fmaf(n0, v0.y, acc.y);
    acc.z = fmaf(n0, v0.z, acc.z);
    acc.w = fmaf(n0, v0.w, acc.w);
  }
  acc.x += __shfl_xor(acc.x, 32);
  acc.y += __shfl_xor(acc.y, 32);
  acc.z += __shfl_xor(acc.z, 32);
  acc.w += __shfl_xor(acc.w, 32);
  if (h == 0) {
    short h0, l0, h1, l1, h2, l2, h3, l3;
    split2(acc.x, h0, l0); split2(acc.y, h1, l1);
    split2(acc.z, h2, l2); split2(acc.w, h3, l3);
    uint2 hp, lp;
    hp.x = (unsigned)(unsigned short)h0 | ((unsigned)(unsigned short)h1 << 16);
    hp.y = (unsigned)(unsigned short)h2 | ((unsigned)(unsigned short)h3 << 16);
    lp.x = (unsigned)(unsigned short)l0 | ((unsigned)(unsigned short)l1 << 16);
    lp.y = (unsigned)(unsigned short)l2 | ((unsigned)(unsigned short)l3 << 16);
    *(uint2*)(aggXh + (size_t)node * 128 + sub * 4) = hp;
    *(uint2*)(aggXl + (size_t)node * 128 + sub * 4) = lp;
  }
}

// ---------------- layer2 aggregate + bias + ELU + bf16 split (float4) ---------

__global__ __launch_bounds__(256) void k_agg2(const int* __restrict__ off,
                                              const int2* __restrict__ c2pack,
                                              const float* __restrict__ h2,
                                              const float* __restrict__ b,
                                              short* __restrict__ xh,
                                              short* __restrict__ xl) {
  int wave = threadIdx.x >> 6, lane = threadIdx.x & 63;
  int h = lane >> 5, sub = lane & 31;
  int node = blockIdx.x * 4 + wave;
  int start = off[node], end = off[node + 1];
  float4 acc = make_float4(0.f, 0.f, 0.f, 0.f);
  int i = start + h;
  for (; i + 14 < end; i += 16) {
    float4 v[8]; float n[8];
#pragma unroll
    for (int k = 0; k < 8; k++) {
      int2 p = c2pack[i + 2 * k];
      n[k] = __int_as_float(p.y);
      v[k] = *(const float4*)(h2 + (size_t)p.x * 128 + sub * 4);
    }
#pragma unroll
    for (int k = 0; k < 8; k++) {
      acc.x = fmaf(n[k], v[k].x, acc.x);
      acc.y = fmaf(n[k], v[k].y, acc.y);
      acc.z = fmaf(n[k], v[k].z, acc.z);
      acc.w = fmaf(n[k], v[k].w, acc.w);
    }
  }
  for (; i < end; i += 2) {
    int2 p = c2pack[i];
    float n0 = __int_as_float(p.y);
    float4 v0 = *(const float4*)(h2 + (size_t)p.x * 128 + sub * 4);
    acc.x = fmaf(n0, v0.x, acc.x);
    acc.y = fmaf(n0, v0.y, acc.y);
    acc.z = fmaf(n0, v0.z, acc.z);
    acc.w = fmaf(n0, v0.w, acc.w);
  }
  acc.x += __shfl_xor(acc.x, 32);
  acc.y += __shfl_xor(acc.y, 32);
  acc.z += __shfl_xor(acc.z, 32);
  acc.w += __shfl_xor(acc.w, 32);
  if (h == 0) {
    float4 bb = *(const float4*)(b + sub * 4);
    float v0 = acc.x + bb.x, v1 = acc.y + bb.y;
    float v2 = acc.z + bb.z, v3 = acc.w + bb.w;
    v0 = v0 > 0.f ? v0 : expm1f(v0);
    v1 = v1 > 0.f ? v1 : expm1f(v1);
    v2 = v2 > 0.f ? v2 : expm1f(v2);
    v3 = v3 > 0.f ? v3 : expm1f(v3);
    short h0, l0, h1, l1, h2s, l2, h3, l3;
    split2(v0, h0, l0); split2(v1, h1, l1);
    split2(v2, h2s, l2); split2(v3, h3, l3);
    uint2 hp, lp;
    hp.x = (unsigned)(unsigned short)h0 | ((unsigned)(unsigned short)h1 << 16);
    hp.y = (unsigned)(unsigned short)h2s | ((unsigned)(unsigned short)h3 << 16);
    lp.x = (unsigned)(unsigned short)l0 | ((unsigned)(unsigned short)l1 << 16);
    lp.y = (unsigned)(unsigned short)l2 | ((unsigned)(unsigned short)l3 << 16);
    *(uint2*)(xh + (size_t)node * 128 + sub * 4) = hp;
    *(uint2*)(xl + (size_t)node * 128 + sub * 4) = lp;
  }
}

// ---------------- fused dense GEMM pair: h2 = (elu(aggX@W_in+b)) @ W_out ------
// 32-node tile; x1 tile (32x256 bf16 hi/lo) lives in LDS between the two
// MFMA phases -> kills the 100 MB x1 global round-trip. LDS 51.2 KB.

__global__ __launch_bounds__(256) void k_gemm12(const short* __restrict__ aggXh,
                                                const short* __restrict__ aggXl,
                                                const short* __restrict__ winth,
                                                const short* __restrict__ wintl,
                                                const float* __restrict__ b,
                                                const short* __restrict__ woutth,
                                                const short* __restrict__ wouttl,
                                                float* __restrict__ h2) {
  __shared__ short Xh[32 * 136];
  __shared__ short Xl[32 * 136];
  __shared__ short Yh[32 * 264];
  __shared__ short Yl[32 * 264];
  int t = threadIdx.x;
  int n0 = blockIdx.x * 32;
#pragma unroll
  for (int j = 0; j < 2; j++) {
    int i = t + 256 * j;
    int row = i >> 4, q = i & 15;
    int node = n0 + row; if (node >= NN) node = NN - 1;
    *(uint4*)&Xh[row * 136 + q * 8] = *(const uint4*)(aggXh + (size_t)node * 128 + q * 8);
    *(uint4*)&Xl[row * 136 + q * 8] = *(const uint4*)(aggXl + (size_t)node * 128 + q * 8);
  }
  __syncthreads();

  int w = t >> 6, lane = t & 63;
  int quad = lane >> 4, l16 = lane & 15;

  // ---- phase 1: x1 = elu(aggX @ W_in + b), wave owns 64 cols -> LDS Y ----
  {
    int nb = w * 64;
    int aoff0 = l16 * 136 + quad * 8;
    int aoff1 = (16 + l16) * 136 + quad * 8;

    f4_t acc[2][4];
#pragma unroll
    for (int mi = 0; mi < 2; mi++)
#pragma unroll
      for (int ni = 0; ni < 4; ni++) acc[mi][ni] = (f4_t){0.f, 0.f, 0.f, 0.f};

#pragma unroll
    for (int kb = 0; kb < 4; kb++) {
      int k0 = kb * 32;
      s8_t ah0 = *(const s8_t*)&Xh[aoff0 + k0];
      s8_t ah1 = *(const s8_t*)&Xh[aoff1 + k0];
      s8_t al0 = *(const s8_t*)&Xl[aoff0 + k0];
      s8_t al1 = *(const s8_t*)&Xl[aoff1 + k0];
#pragma unroll
      for (int ni = 0; ni < 4; ni++) {
        int bo = (nb + ni * 16 + l16) * 128 + quad * 8 + k0;
        s8_t bh = *(const s8_t*)(winth + bo);
        s8_t bl = *(const s8_t*)(wintl + bo);
        acc[0][ni] = __builtin_amdgcn_mfma_f32_16x16x32_bf16(ah0, bh, acc[0][ni], 0, 0, 0);
        acc[0][ni] = __builtin_amdgcn_mfma_f32_16x16x32_bf16(ah0, bl, acc[0][ni], 0, 0, 0);
        acc[0][ni] = __builtin_amdgcn_mfma_f32_16x16x32_bf16(al0, bh, acc[0][ni], 0, 0, 0);
        acc[1][ni] = __builtin_amdgcn_mfma_f32_16x16x32_bf16(ah1, bh, acc[1][ni], 0, 0, 0);
        acc[1][ni] = __builtin_amdgcn_mfma_f32_16x16x32_bf16(ah1, bl, acc[1][ni], 0, 0, 0);
        acc[1][ni] = __builtin_amdgcn_mfma_f32_16x16x32_bf16(al1, bh, acc[1][ni], 0, 0, 0);
      }
    }

#pragma unroll
    for (int mi = 0; mi < 2; mi++)
#pragma unroll
      for (int ni = 0; ni < 4; ni++) {
        int col = nb + ni * 16 + l16;
        float bv = b[col];
#pragma unroll
        for (int r = 0; r < 4; r++) {
          int row = mi * 16 + quad * 4 + r;
          float v = acc[mi][ni][r] + bv;
          v = v > 0.f ? v : expm1f(v);
          short hh, ll; split2(v, hh, ll);
          Yh[row * 264 + col] = hh;
          Yl[row * 264 + col] = ll;
        }
      }
  }
  __syncthreads();

  // ---- phase 2: h2 = x1 @ W_out, wave owns 32 cols ----
  {
    int nb = w * 32;
    int aoff0 = l16 * 264 + quad * 8;
    int aoff1 = (16 + l16) * 264 + quad * 8;

    f4_t acc[2][2];
#pragma unroll
    for (int mi = 0; mi < 2; mi++)
#pragma unroll
      for (int ni = 0; ni < 2; ni++) acc[mi][ni] = (f4_t){0.f, 0.f, 0.f, 0.f};

#pragma unroll
    for (int kb = 0; kb < 8; kb++) {
      int k0 = kb * 32;
      s8_t ah0 = *(const s8_t*)&Yh[aoff0 + k0];
      s8_t ah1 = *(const s8_t*)&Yh[aoff1 + k0];
      s8_t al0 = *(const s8_t*)&Yl[aoff0 + k0];
      s8_t al1 = *(const s8_t*)&Yl[aoff1 + k0];
#pragma unroll
      for (int ni = 0; ni < 2; ni++) {
        int bo = (nb + ni * 16 + l16) * 256 + quad * 8 + k0;
        s8_t bh = *(const s8_t*)(woutth + bo);
        s8_t bl = *(const s8_t*)(wouttl + bo);
        acc[0][ni] = __builtin_amdgcn_mfma_f32_16x16x32_bf16(ah0, bh, acc[0][ni], 0, 0, 0);
        acc[0][ni] = __builtin_amdgcn_mfma_f32_16x16x32_bf16(ah0, bl, acc[0][ni], 0, 0, 0);
        acc[0][ni] = __builtin_amdgcn_mfma_f32_16x16x32_bf16(al0, bh, acc[0][ni], 0, 0, 0);
        acc[1][ni] = __builtin_amdgcn_mfma_f32_16x16x32_bf16(ah1, bh, acc[1][ni], 0, 0, 0);
        acc[1][ni] = __builtin_amdgcn_mfma_f32_16x16x32_bf16(ah1, bl, acc[1][ni], 0, 0, 0);
        acc[1][ni] = __builtin_amdgcn_mfma_f32_16x16x32_bf16(al1, bh, acc[1][ni], 0, 0, 0);
      }
    }

#pragma unroll
    for (int mi = 0; mi < 2; mi++)
#pragma unroll
      for (int ni = 0; ni < 2; ni++) {
        int col = nb + ni * 16 + l16;
#pragma unroll
        for (int r = 0; r < 4; r++) {
          int node = n0 + mi * 16 + quad * 4 + r;
          if (node < NN) h2[(size_t)node * 128 + col] = acc[mi][ni][r];
        }
      }
  }
}

// ---------------- node-level decoder-layer1 factorization ----------------

__global__ __launch_bounds__(256) void k_pab(const short* __restrict__ x2h,
                                             const short* __restrict__ x2l,
                                             const short* __restrict__ w1th,
                                             const short* __restrict__ w1tl,
                                             const float* __restrict__ b1,
                                             float* __restrict__ Pa,
                                             float* __restrict__ Pb) {
  __shared__ short Xh[32 * 136];
  __shared__ short Xl[32 * 136];
  int t = threadIdx.x;
  int n0 = blockIdx.x * 32;
#pragma unroll
  for (int j = 0; j < 2; j++) {
    int i = t + 256 * j;
    int row = i >> 4, q = i & 15;
    int node = n0 + row; if (node >= NN) node = NN - 1;
    *(uint4*)&Xh[row * 136 + q * 8] = *(const uint4*)(x2h + (size_t)node * 128 + q * 8);
    *(uint4*)&Xl[row * 136 + q * 8] = *(const uint4*)(x2l + (size_t)node * 128 + q * 8);
  }
  __syncthreads();

  int w = t >> 6, lane = t & 63;
  int quad = lane >> 4, l16 = lane & 15;
  int nb = w * 32;
  int aoff0 = l16 * 136 + quad * 8;
  int aoff1 = (16 + l16) * 136 + quad * 8;
  int bo0 = (nb + l16) * 256 + quad * 8;
  int bo1 = (nb + 16 + l16) * 256 + quad * 8;

  f4_t aa[2][2], ab[2][2];
#pragma unroll
  for (int mi = 0; mi < 2; mi++)
#pragma unroll
    for (int ni = 0; ni < 2; ni++) {
      aa[mi][ni] = (f4_t){0.f, 0.f, 0.f, 0.f};
      ab[mi][ni] = (f4_t){0.f, 0.f, 0.f, 0.f};
    }

#pragma unroll
  for (int kb = 0; kb < 4; kb++) {
    int k0 = kb * 32;
    s8_t ah0 = *(const s8_t*)&Xh[aoff0 + k0];
    s8_t ah1 = *(const s8_t*)&Xh[aoff1 + k0];
    s8_t al0 = *(const s8_t*)&Xl[aoff0 + k0];
    s8_t al1 = *(const s8_t*)&Xl[aoff1 + k0];
    {
      s8_t bh0 = *(const s8_t*)(w1th + bo0 + k0);
      s8_t bh1 = *(const s8_t*)(w1th + bo1 + k0);
      s8_t bl0 = *(const s8_t*)(w1tl + bo0 + k0);
      s8_t bl1 = *(const s8_t*)(w1tl + bo1 + k0);
      aa[0][0] = __builtin_amdgcn_mfma_f32_16x16x32_bf16(ah0, bh0, aa[0][0], 0, 0, 0);
      aa[0][0] = __builtin_amdgcn_mfma_f32_16x16x32_bf16(ah0, bl0, aa[0][0], 0, 0, 0);
      aa[0][0] = __builtin_amdgcn_mfma_f32_16x16x32_bf16(al0, bh0, aa[0][0], 0, 0, 0);
      aa[0][1] = __builtin_amdgcn_mfma_f32_16x16x32_bf16(ah0, bh1, aa[0][1], 0, 0, 0);
      aa[0][1] = __builtin_amdgcn_mfma_f32_16x16x32_bf16(ah0, bl1, aa[0][1], 0, 0, 0);
      aa[0][1] = __builtin_amdgcn_mfma_f32_16x16x32_bf16(al0, bh1, aa[0][1], 0, 0, 0);
      aa[1][0] = __builtin_amdgcn_mfma_f32_16x16x32_bf16(ah1, bh0, aa[1][0], 0, 0, 0);
      aa[1][0] = __builtin_amdgcn_mfma_f32_16x16x32_bf16(ah1, bl0, aa[1][0], 0, 0, 0);
      aa[1][0] = __builtin_amdgcn_mfma_f32_16x16x32_bf16(al1, bh0, aa[1][0], 0, 0, 0);
      aa[1][1] = __builtin_amdgcn_mfma_f32_16x16x32_bf16(ah1, bh1, aa[1][1], 0, 0, 0);
      aa[1][1] = __builtin_amdgcn_mfma_f32_16x16x32_bf16(ah1, bl1, aa[1][1], 0, 0, 0);
      aa[1][1] = __builtin_amdgcn_mfma_f32_16x16x32_bf16(al1, bh1, aa[1][1], 0, 0, 0);
    }
    {
      s8_t bh0 = *(const s8_t*)(w1th + bo0 + 128 + k0);
      s8_t bh1 = *(const s8_t*)(w1th + bo1 + 128 + k0);
      s8_t bl0 = *(const s8_t*)(w1tl + bo0 + 128 + k0);
      s8_t bl1 = *(const s8_t*)(w1tl + bo1 + 128 + k0);
      ab[0][0] = __builtin_amdgcn_mfma_f32_16x16x32_bf16(ah0, bh0, ab[0][0], 0, 0, 0);
      ab[0][0] = __builtin_amdgcn_mfma_f32_16x16x32_bf16(ah0, bl0, ab[0][0], 0, 0, 0);
      ab[0][0] = __builtin_amdgcn_mfma_f32_16x16x32_bf16(al0, bh0, ab[0][0], 0, 0, 0);
      ab[0][1] = __builtin_amdgcn_mfma_f32_16x16x32_bf16(ah0, bh1, ab[0][1], 0, 0, 0);
      ab[0][1] = __builtin_amdgcn_mfma_f32_16x16x32_bf16(ah0, bl1, ab[0][1], 0, 0, 0);
      ab[0][1] = __builtin_amdgcn_mfma_f32_16x16x32_bf16(al0, bh1, ab[0][1], 0, 0, 0);
      ab[1][0] = __builtin_amdgcn_mfma_f32_16x16x32_bf16(ah1, bh0, ab[1][0], 0, 0, 0);
      ab[1][0] = __builtin_amdgcn_mfma_f32_16x16x32_bf16(ah1, bl0, ab[1][0], 0, 0, 0);
      ab[1][0] = __builtin_amdgcn_mfma_f32_16x16x32_bf16(al1, bh0, ab[1][0], 0, 0, 0);
      ab[1][1] = __builtin_amdgcn_mfma_f32_16x16x32_bf16(ah1, bh1, ab[1][1], 0, 0, 0);
      ab[1][1] = __builtin_amdgcn_mfma_f32_16x16x32_bf16(ah1, bl1, ab[1][1], 0, 0, 0);
      ab[1][1] = __builtin_amdgcn_mfma_f32_16x16x32_bf16(al1, bh1, ab[1][1], 0, 0, 0);
    }
  }

  float b1v0 = b1[nb + l16], b1v1 = b1[nb + 16 + l16];
#pragma unroll
  for (int mi = 0; mi < 2; mi++)
#pragma unroll
    for (int ni = 0; ni < 2; ni++) {
      int col = nb + ni * 16 + l16;
      float bv = ni ? b1v1 : b1v0;
#pragma unroll
      for (int r = 0; r < 4; r++) {
        int node = n0 + mi * 16 + quad * 4 + r;
        if (node < NN) {
          Pa[(size_t)node * 128 + col] = aa[mi][ni][r];
          Pb[(size_t)node * 128 + col] = ab[mi][ni][r] + bv;
        }
      }
    }
}

// ---------------- fused edge decoder v9 (unchanged, measured 235 us) ----------

#define ST 136   // t1 LDS stride (shorts)

__global__ __launch_bounds__(256, 4) void k_decoder(
    const float* __restrict__ Pa, const float* __restrict__ Pb,
    const int4* __restrict__ c1pack,
    const short* __restrict__ w2th, const short* __restrict__ w2tl,
    const float* __restrict__ b2,
    const float* __restrict__ W3, const float* __restrict__ b3,
    float* __restrict__ out) {
  __shared__ short Th[32 * ST];
  __shared__ short Tl[32 * ST];
  __shared__ float part[4][32];

  int t = threadIdx.x;
  int b = blockIdx.x;
  int id = (b & 7) * 3125 + (b >> 3);   // XCD-contiguous CSR ranges
  int s0base = id * 32;

  {
    int le0 = t >> 4, q = t & 15;
    int4 p0 = c1pack[s0base + le0];
    int4 p1 = c1pack[s0base + le0 + 16];
    const float* pa0 = Pa + (size_t)p0.x * 128 + q * 8;
    const float* pb0 = Pb + (size_t)p0.y * 128 + q * 8;
    const float* pa1 = Pa + (size_t)p1.x * 128 + q * 8;
    const float* pb1 = Pb + (size_t)p1.y * 128 + q * 8;
    float4 ra0 = *(const float4*)(pa0);
    float4 ra1 = *(const float4*)(pa0 + 4);
    float4 rb0 = *(const float4*)(pb0);
    float4 rb1 = *(const float4*)(pb0 + 4);
    float4 ra2 = *(const float4*)(pa1);
    float4 ra3 = *(const float4*)(pa1 + 4);
    float4 rb2 = *(const float4*)(pb1);
    float4 rb3 = *(const float4*)(pb1 + 4);

    float v0[8], v1[8];
    v0[0] = ra0.x + rb0.x; v0[1] = ra0.y + rb0.y;
    v0[2] = ra0.z + rb0.z; v0[3] = ra0.w + rb0.w;
    v0[4] = ra1.x + rb1.x; v0[5] = ra1.y + rb1.y;
    v0[6] = ra1.z + rb1.z; v0[7] = ra1.w + rb1.w;
    v1[0] = ra2.x + rb2.x; v1[1] = ra2.y + rb2.y;
    v1[2] = ra2.z + rb2.z; v1[3] = ra2.w + rb2.w;
    v1[4] = ra3.x + rb3.x; v1[5] = ra3.y + rb3.y;
    v1[6] = ra3.z + rb3.z; v1[7] = ra3.w + rb3.w;

    s8_t hv0, lv0, hv1, lv1;
#pragma unroll
    for (int k = 0; k < 8; k++) {
      float x0 = fmaxf(v0[k], 0.f);
      float x1 = fmaxf(v1[k], 0.f);
      short hh, ll;
      split2(x0, hh, ll); hv0[k] = hh; lv0[k] = ll;
      split2(x1, hh, ll); hv1[k] = hh; lv1[k] = ll;
    }
    *(s8_t*)&Th[le0 * ST + q * 8] = hv0;
    *(s8_t*)&Tl[le0 * ST + q * 8] = lv0;
    *(s8_t*)&Th[(le0 + 16) * ST + q * 8] = hv1;
    *(s8_t*)&Tl[(le0 + 16) * ST + q * 8] = lv1;
  }
  __syncthreads();

  int w = t >> 6, lane = t & 63;
  int quad = lane >> 4, l16 = lane & 15;
  int nb = w * 32;
  float b2v0 = b2[nb + l16], b2v1 = b2[nb + 16 + l16];
  float w3a = W3[nb + l16], w3b = W3[nb + 16 + l16];

  int toff0 = l16 * ST + quad * 8;
  int toff1 = (16 + l16) * ST + quad * 8;
  int coff0 = (nb + l16) * 128 + quad * 8;
  int coff1 = (nb + 16 + l16) * 128 + quad * 8;

  f4_t acc2[2][2];
#pragma unroll
  for (int mi = 0; mi < 2; mi++)
#pragma unroll
    for (int ni = 0; ni < 2; ni++) acc2[mi][ni] = (f4_t){0.f, 0.f, 0.f, 0.f};

#pragma unroll
  for (int kb = 0; kb < 4; kb++) {
    int k0 = kb * 32;
    s8_t ah0 = *(const s8_t*)&Th[toff0 + k0];
    s8_t ah1 = *(const s8_t*)&Th[toff1 + k0];
    s8_t al0 = *(const s8_t*)&Tl[toff0 + k0];
    s8_t al1 = *(const s8_t*)&Tl[toff1 + k0];
    s8_t bh0 = *(const s8_t*)(w2th + coff0 + k0);
    s8_t bh1 = *(const s8_t*)(w2th + coff1 + k0);
    s8_t bl0 = *(const s8_t*)(w2tl + coff0 + k0);
    s8_t bl1 = *(const s8_t*)(w2tl + coff1 + k0);
    acc2[0][0] = __builtin_amdgcn_mfma_f32_16x16x32_bf16(ah0, bh0, acc2[0][0], 0, 0, 0);
    acc2[0][0] = __builtin_amdgcn_mfma_f32_16x16x32_bf16(ah0, bl0, acc2[0][0], 0, 0, 0);
    acc2[0][0] = __builtin_amdgcn_mfma_f32_16x16x32_bf16(al0, bh0, acc2[0][0], 0, 0, 0);
    acc2[0][1] = __builtin_amdgcn_mfma_f32_16x16x32_bf16(ah0, bh1, acc2[0][1], 0, 0, 0);
    acc2[0][1] = __builtin_amdgcn_mfma_f32_16x16x32_bf16(ah0, bl1, acc2[0][1], 0, 0, 0);
    acc2[0][1] = __builtin_amdgcn_mfma_f32_16x16x32_bf16(al0, bh1, acc2[0][1], 0, 0, 0);
    acc2[1][0] = __builtin_amdgcn_mfma_f32_16x16x32_bf16(ah1, bh0, acc2[1][0], 0, 0, 0);
    acc2[1][0] = __builtin_amdgcn_mfma_f32_16x16x32_bf16(ah1, bl0, acc2[1][0], 0, 0, 0);
    acc2[1][0] = __builtin_amdgcn_mfma_f32_16x16x32_bf16(al1, bh0, acc2[1][0], 0, 0, 0);
    acc2[1][1] = __builtin_amdgcn_mfma_f32_16x16x32_bf16(ah1, bh1, acc2[1][1], 0, 0, 0);
    acc2[1][1] = __builtin_amdgcn_mfma_f32_16x16x32_bf16(ah1, bl1, acc2[1][1], 0, 0, 0);
    acc2[1][1] = __builtin_amdgcn_mfma_f32_16x16x32_bf16(al1, bh1, acc2[1][1], 0, 0, 0);
  }

#pragma unroll
  for (int mi = 0; mi < 2; mi++) {
#pragma unroll
    for (int r = 0; r < 4; r++) {
      float pv = fmaxf(acc2[mi][0][r] + b2v0, 0.f) * w3a +
                 fmaxf(acc2[mi][1][r] + b2v1, 0.f) * w3b;
      pv += __shfl_xor(pv, 1);
      pv += __shfl_xor(pv, 2);
      pv += __shfl_xor(pv, 4);
      pv += __shfl_xor(pv, 8);
      if (l16 == 0) part[w][mi * 16 + quad * 4 + r] = pv;
    }
  }
  __syncthreads();

  if (t < 32) {
    float s = part[0][t] + part[1][t] + part[2][t] + part[3][t] + b3[0];
    int4 p = c1pack[s0base + t];
    out[p.z] = s;
  }
}

// ---------------- launch ----------------

extern "C" void kernel_launch(void* const* d_in, const int* in_sizes, int n_in,
                              void* d_out, int out_size, void* d_ws, size_t ws_size,
                              hipStream_t stream) {
  const int*   node_ids = (const int*)d_in[0];
  const int*   ei       = (const int*)d_in[1];
  const int*   nei      = (const int*)d_in[2];
  const float* eattr    = (const float*)d_in[3];
  const float* emb      = (const float*)d_in[4];
  const float* W_in     = (const float*)d_in[5];
  const float* b_in     = (const float*)d_in[6];
  const float* W_out    = (const float*)d_in[7];
  const float* b_out    = (const float*)d_in[8];
  const float* W1       = (const float*)d_in[9];
  const float* b1       = (const float*)d_in[10];
  const float* W2       = (const float*)d_in[11];
  const float* b2       = (const float*)d_in[12];
  const float* W3       = (const float*)d_in[13];
  const float* b3       = (const float*)d_in[14];
  float* out = (float*)d_out;

  // workspace layout (floats)
  float* ws    = (float*)d_ws;
  float* bufA  = ws;                          // N*128 f: aggXh/l -> Pa
  float* bufB  = bufA + (size_t)NN * 128;     // N*256 f: [h2 -> Pb | x2h/x2l]
  int*   cnt1  = (int*)(bufB + (size_t)NN * 256);
  int*   cnt2  = cnt1 + NN;
  float* deg1  = (float*)(cnt2 + NN);
  float* dinv1 = deg1 + NN;
  float* dinv2 = dinv1 + NN;
  int*   off1  = (int*)(dinv2 + NN);          // N+1
  int*   pos1  = off1 + NN + 1;               // N
  int*   off2  = pos1 + NN;                   // N+1
  int*   pos2  = off2 + NN + 1;               // N
  int4*  c1pack = (int4*)((((uintptr_t)(pos2 + NN)) + 15) & ~(uintptr_t)15);  // E
  int2*  c2pack = (int2*)(c1pack + NE);                                       // E
  short* w1th   = (short*)(c2pack + NE);
  short* w1tl   = w1th + 32768;
  short* w2th   = w1tl + 32768;
  short* w2tl   = w2th + 16384;
  short* winth  = w2tl + 16384;
  short* wintl  = winth + 32768;
  short* woutth = wintl + 32768;
  short* wouttl = woutth + 32768;
  int*   part   = (int*)(wouttl + 32768);     // 2*NCHUNK

  short* aggXh = (short*)bufA;                // N*128 shorts
  short* aggXl = aggXh + (size_t)NN * 128;
  float* Pa    = bufA;                        // overwrites aggX (dead after gemm12)
  float* h2    = bufB;                        // first half of bufB
  float* Pb    = bufB;                        // overwrites h2 (dead after agg2)
  short* x2h   = (short*)(bufB + (size_t)NN * 128);  // second half of bufB
  short* x2l   = x2h + (size_t)NN * 128;

  // weight split (W1, W2, W_in^T, W_out^T)
  k_wcvt<<<448, 256, 0, stream>>>(W1, W2, W_in, W_out,
                                  w1th, w1tl, w2th, w2tl,
                                  winth, wintl, woutth, wouttl);

  // CSR build: hist -> scan(3-phase, dinv fused) -> fill
  hipMemsetAsync(cnt1, 0, 3 * (size_t)NN * sizeof(int), stream);  // cnt1,cnt2,deg1
  k_hist<<<NE / 256, 256, 0, stream>>>(ei, nei, eattr, cnt1, deg1, cnt2);
  k_scan_part<<<2 * NCHUNK, 256, 0, stream>>>(cnt1, cnt2, deg1, dinv1, dinv2, part);
  k_scan_mid<<<1, 256, 0, stream>>>(part, off1 + NN, off2 + NN);
  k_scan_final<<<2 * NCHUNK, 256, 0, stream>>>(cnt1, cnt2, part,
                                               off1, pos1, off2, pos2);
  k_fill<<<NE / 256, 256, 0, stream>>>(ei, nei, eattr, dinv1, dinv2,
                                       pos1, c1pack, pos2, c2pack);

  // layer 1: aggregate (12500 independent blocks) -> fused GEMM1+GEMM2
  k_agg1<<<NN / 4, 256, 0, stream>>>(off1, c1pack, node_ids, emb, aggXh, aggXl);
  k_gemm12<<<(NN + 31) / 32, 256, 0, stream>>>(aggXh, aggXl, winth, wintl, b_in,
                                               woutth, wouttl, h2);

  // layer 2: aggregate h2 (+bias+ELU+split fused) -> x2
  k_agg2<<<NN / 4, 256, 0, stream>>>(off2, c2pack, h2, b_out, x2h, x2l);

  // decoder layer-1 factorization: Pa/Pb per node (b1 folded into Pb)
  k_pab<<<(NN + 31) / 32, 256, 0, stream>>>(x2h, x2l, w1th, w1tl, b1, Pa, Pb);

  // decoder v9 (unchanged)
  k_decoder<<<NE / 32, 256, 0, stream>>>(Pa, Pb, c1pack,
                                         w2th, w2tl, b2, W3, b3, out);
}

// Round 13
// 724.167 us; speedup vs baseline: 1.1018x; 1.0084x over previous
//
#include <hip/hip_runtime.h>
#include <math.h>

#define NN 50000
#define NE 800000
// D = 128, H = 256

typedef __attribute__((ext_vector_type(8))) short s8_t;   // 8 bf16
typedef __attribute__((ext_vector_type(4))) float f4_t;   // 4 fp32

__device__ __forceinline__ short bf16_rne(float v) {
  unsigned u = __float_as_uint(v);
  unsigned r = (u + 0x7FFFu + ((u >> 16) & 1u)) >> 16;
  return (short)r;
}
__device__ __forceinline__ float bf16_tof(short h) {
  return __uint_as_float(((unsigned)(unsigned short)h) << 16);
}
__device__ __forceinline__ void split2(float v, short& hi, short& lo) {
  hi = bf16_rne(v);
  lo = bf16_rne(v - bf16_tof(hi));
}

// ---------------- weight split/transpose (W1, W2, W_in, W_out) ----------------

__global__ __launch_bounds__(256) void k_wcvt(const float* __restrict__ W1,
                                              const float* __restrict__ W2,
                                              const float* __restrict__ W_in,
                                              const float* __restrict__ W_out,
                                              short* __restrict__ w1th,
                                              short* __restrict__ w1tl,
                                              short* __restrict__ w2th,
                                              short* __restrict__ w2tl,
                                              short* __restrict__ winth,
                                              short* __restrict__ wintl,
                                              short* __restrict__ woutth,
                                              short* __restrict__ wouttl) {
  int i = blockIdx.x * 256 + threadIdx.x;
  if (i < 32768) {                    // W1 [256,128] -> [128][256]
    int k = i >> 7, n = i & 127;
    short h, l; split2(W1[i], h, l);
    w1th[n * 256 + k] = h; w1tl[n * 256 + k] = l;
  } else if (i < 49152) {             // W2 [128,128] -> [128][128]
    int j = i - 32768;
    int k = j >> 7, n = j & 127;
    short h, l; split2(W2[j], h, l);
    w2th[n * 128 + k] = h; w2tl[n * 128 + k] = l;
  } else if (i < 81920) {             // W_in [128,256] -> [256][128]
    int j = i - 49152;
    int k = j >> 8, n = j & 255;
    short h, l; split2(W_in[j], h, l);
    winth[n * 128 + k] = h; wintl[n * 128 + k] = l;
  } else if (i < 114688) {            // W_out [256,128] -> [128][256]
    int j = i - 81920;
    int k = j >> 7, n = j & 127;
    short h, l; split2(W_out[j], h, l);
    woutth[n * 256 + k] = h; wouttl[n * 256 + k] = l;
  }
}

// ---------------- CSR build: histogram ----------------

__global__ __launch_bounds__(256) void k_hist(const int* __restrict__ ei,
                                              const int* __restrict__ nei,
                                              const float* __restrict__ w,
                                              int* __restrict__ cnt1,
                                              float* __restrict__ deg1,
                                              int* __restrict__ cnt2) {
  int e = blockIdx.x * 256 + threadIdx.x;
  if (e < NE) {
    int c1 = ei[NE + e];
    atomicAdd(&cnt1[c1], 1);
    atomicAdd(&deg1[c1], w[e]);
    atomicAdd(&cnt2[nei[NE + e]], 1);
  }
}

// ---------------- hierarchical exclusive scan (+ dinv fused in part phase) ----

#define NCHUNK 196   // ceil(50000/256)

__global__ __launch_bounds__(256) void k_scan_part(const int* __restrict__ cnt1,
                                                   const int* __restrict__ cnt2,
                                                   const float* __restrict__ deg1,
                                                   float* __restrict__ dinv1,
                                                   float* __restrict__ dinv2,
                                                   int* __restrict__ part) {
  int g = blockIdx.x >= NCHUNK;
  int chunk = g ? blockIdx.x - NCHUNK : blockIdx.x;
  const int* cnt = g ? cnt2 : cnt1;
  int i = chunk * 256 + threadIdx.x;
  int v = (i < NN) ? cnt[i] : 0;
  if (i < NN) {
    if (!g) {
      float d1 = deg1[i];
      dinv1[i] = d1 > 0.f ? (1.0f / sqrtf(d1)) : 0.f;
    } else {
      dinv2[i] = v > 0 ? (1.0f / sqrtf((float)v)) : 0.f;
    }
  }
  __shared__ int sd[4];
  int r = v;
#pragma unroll
  for (int o = 32; o; o >>= 1) r += __shfl_down(r, o);
  if ((threadIdx.x & 63) == 0) sd[threadIdx.x >> 6] = r;
  __syncthreads();
  if (threadIdx.x == 0) part[blockIdx.x] = sd[0] + sd[1] + sd[2] + sd[3];
}

__global__ __launch_bounds__(256) void k_scan_mid(int* __restrict__ part,
                                                  int* __restrict__ off1_last,
                                                  int* __restrict__ off2_last) {
  __shared__ int sd[256];
  for (int g = 0; g < 2; g++) {
    int base = g * NCHUNK;
    int v = (threadIdx.x < NCHUNK) ? part[base + threadIdx.x] : 0;
    sd[threadIdx.x] = v;
    __syncthreads();
    for (int o = 1; o < 256; o <<= 1) {
      int x = (threadIdx.x >= o) ? sd[threadIdx.x - o] : 0;
      __syncthreads();
      sd[threadIdx.x] += x;
      __syncthreads();
    }
    if (threadIdx.x < NCHUNK) part[base + threadIdx.x] = sd[threadIdx.x] - v;
    if (threadIdx.x == 255) *(g ? off2_last : off1_last) = sd[255];
    __syncthreads();
  }
}

__global__ __launch_bounds__(256) void k_scan_final(const int* __restrict__ cnt1,
                                                    const int* __restrict__ cnt2,
                                                    const int* __restrict__ part,
                                                    int* __restrict__ off1,
                                                    int* __restrict__ pos1,
                                                    int* __restrict__ off2,
                                                    int* __restrict__ pos2) {
  int g = blockIdx.x >= NCHUNK;
  int chunk = g ? blockIdx.x - NCHUNK : blockIdx.x;
  const int* cnt = g ? cnt2 : cnt1;
  int* off = g ? off2 : off1;
  int* pos = g ? pos2 : pos1;
  __shared__ int sd[256];
  int i = chunk * 256 + threadIdx.x;
  int v = (i < NN) ? cnt[i] : 0;
  sd[threadIdx.x] = v;
  __syncthreads();
  for (int o = 1; o < 256; o <<= 1) {
    int x = (threadIdx.x >= o) ? sd[threadIdx.x - o] : 0;
    __syncthreads();
    sd[threadIdx.x] += x;
    __syncthreads();
  }
  if (i < NN) {
    int ex = part[blockIdx.x] + sd[threadIdx.x] - v;
    off[i] = ex; pos[i] = ex;
  }
}

// ---------------- fill CSR (packed records) ----------------
// c1pack: {src|dst<<16, emb_row(=ids[src]), eid, nrm}  (NN < 2^16)
// ids lookup done HERE (store-bound kernel) so agg1's gather chain loses a hop.

__global__ __launch_bounds__(256) void k_fill(const int* __restrict__ ei,
                                              const int* __restrict__ nei,
                                              const float* __restrict__ w,
                                              const int* __restrict__ ids,
                                              const float* __restrict__ dinv1,
                                              const float* __restrict__ dinv2,
                                              int* __restrict__ pos1,
                                              int4* __restrict__ c1pack,
                                              int* __restrict__ pos2,
                                              int2* __restrict__ c2pack) {
  int e = blockIdx.x * 256 + threadIdx.x;
  if (e < NE) {
    int r = ei[e], c = ei[NE + e];
    float nv = dinv1[r] * w[e] * dinv1[c];
    int s = atomicAdd(&pos1[c], 1);
    int packed = (int)((unsigned)r | ((unsigned)c << 16));
    c1pack[s] = make_int4(packed, ids[r], e, __float_as_int(nv));
    int r2 = nei[e], c2v = nei[NE + e];
    float nv2 = dinv2[r2] * dinv2[c2v];
    int s2 = atomicAdd(&pos2[c2v], 1);
    c2pack[s2] = make_int2(r2, __float_as_int(nv2));
  }
}

// ---------------- layer1 aggregate: float4 half-wave, bf16-split output -------
// One wave per node; emb row index pre-resolved in c1pack.y (no ids hop).

__global__ __launch_bounds__(256) void k_agg1(const int* __restrict__ off,
                                              const int4* __restrict__ c1pack,
                                              const float* __restrict__ emb,
                                              short* __restrict__ aggXh,
                                              short* __restrict__ aggXl) {
  int wave = threadIdx.x >> 6, lane = threadIdx.x & 63;
  int h = lane >> 5, sub = lane & 31;
  int node = blockIdx.x * 4 + wave;
  int start = off[node], end = off[node + 1];
  float4 acc = make_float4(0.f, 0.f, 0.f, 0.f);
  int i = start + h;
  for (; i + 14 < end; i += 16) {
    float4 v[8]; float n[8];
#pragma unroll
    for (int k = 0; k < 8; k++) {
      int4 p = c1pack[i + 2 * k];
      n[k] = __int_as_float(p.w);
      v[k] = *(const float4*)(emb + (size_t)p.y * 128 + sub * 4);
    }
#pragma unroll
    for (int k = 0; k < 8; k++) {
      acc.x = fmaf(n[k], v[k].x, acc.x);
      acc.y = fmaf(n[k], v[k].y, acc.y);
      acc.z = fmaf(n[k], v[k].z, acc.z);
      acc.w = fmaf(n[k], v[k].w, acc.w);
    }
  }
  for (; i < end; i += 2) {
    int4 p = c1pack[i];
    float n0 = __int_as_float(p.w);
    float4 v0 = *(const float4*)(emb + (size_t)p.y * 128 + sub * 4);
    acc.x = fmaf(n0, v0.x, acc.x);
    acc.y = fmaf(n0, v0.y, acc.y);
    acc.z = fmaf(n0, v0.z, acc.z);
    acc.w = fmaf(n0, v0.w, acc.w);
  }
  acc.x += __shfl_xor(acc.x, 32);
  acc.y += __shfl_xor(acc.y, 32);
  acc.z += __shfl_xor(acc.z, 32);
  acc.w += __shfl_xor(acc.w, 32);
  if (h == 0) {
    short h0, l0, h1, l1, h2, l2, h3, l3;
    split2(acc.x, h0, l0); split2(acc.y, h1, l1);
    split2(acc.z, h2, l2); split2(acc.w, h3, l3);
    uint2 hp, lp;
    hp.x = (unsigned)(unsigned short)h0 | ((unsigned)(unsigned short)h1 << 16);
    hp.y = (unsigned)(unsigned short)h2 | ((unsigned)(unsigned short)h3 << 16);
    lp.x = (unsigned)(unsigned short)l0 | ((unsigned)(unsigned short)l1 << 16);
    lp.y = (unsigned)(unsigned short)l2 | ((unsigned)(unsigned short)l3 << 16);
    *(uint2*)(aggXh + (size_t)node * 128 + sub * 4) = hp;
    *(uint2*)(aggXl + (size_t)node * 128 + sub * 4) = lp;
  }
}

// ---------------- layer2 aggregate + bias + ELU + bf16 split (float4) ---------

__global__ __launch_bounds__(256) void k_agg2(const int* __restrict__ off,
                                              const int2* __restrict__ c2pack,
                                              const float* __restrict__ h2,
                                              const float* __restrict__ b,
                                              short* __restrict__ xh,
                                              short* __restrict__ xl) {
  int wave = threadIdx.x >> 6, lane = threadIdx.x & 63;
  int h = lane >> 5, sub = lane & 31;
  int node = blockIdx.x * 4 + wave;
  int start = off[node], end = off[node + 1];
  float4 acc = make_float4(0.f, 0.f, 0.f, 0.f);
  int i = start + h;
  for (; i + 14 < end; i += 16) {
    float4 v[8]; float n[8];
#pragma unroll
    for (int k = 0; k < 8; k++) {
      int2 p = c2pack[i + 2 * k];
      n[k] = __int_as_float(p.y);
      v[k] = *(const float4*)(h2 + (size_t)p.x * 128 + sub * 4);
    }
#pragma unroll
    for (int k = 0; k < 8; k++) {
      acc.x = fmaf(n[k], v[k].x, acc.x);
      acc.y = fmaf(n[k], v[k].y, acc.y);
      acc.z = fmaf(n[k], v[k].z, acc.z);
      acc.w = fmaf(n[k], v[k].w, acc.w);
    }
  }
  for (; i < end; i += 2) {
    int2 p = c2pack[i];
    float n0 = __int_as_float(p.y);
    float4 v0 = *(const float4*)(h2 + (size_t)p.x * 128 + sub * 4);
    acc.x = fmaf(n0, v0.x, acc.x);
    acc.y = fmaf(n0, v0.y, acc.y);
    acc.z = fmaf(n0, v0.z, acc.z);
    acc.w = fmaf(n0, v0.w, acc.w);
  }
  acc.x += __shfl_xor(acc.x, 32);
  acc.y += __shfl_xor(acc.y, 32);
  acc.z += __shfl_xor(acc.z, 32);
  acc.w += __shfl_xor(acc.w, 32);
  if (h == 0) {
    float4 bb = *(const float4*)(b + sub * 4);
    float v0 = acc.x + bb.x, v1 = acc.y + bb.y;
    float v2 = acc.z + bb.z, v3 = acc.w + bb.w;
    v0 = v0 > 0.f ? v0 : expm1f(v0);
    v1 = v1 > 0.f ? v1 : expm1f(v1);
    v2 = v2 > 0.f ? v2 : expm1f(v2);
    v3 = v3 > 0.f ? v3 : expm1f(v3);
    short h0, l0, h1, l1, h2s, l2, h3, l3;
    split2(v0, h0, l0); split2(v1, h1, l1);
    split2(v2, h2s, l2); split2(v3, h3, l3);
    uint2 hp, lp;
    hp.x = (unsigned)(unsigned short)h0 | ((unsigned)(unsigned short)h1 << 16);
    hp.y = (unsigned)(unsigned short)h2s | ((unsigned)(unsigned short)h3 << 16);
    lp.x = (unsigned)(unsigned short)l0 | ((unsigned)(unsigned short)l1 << 16);
    lp.y = (unsigned)(unsigned short)l2 | ((unsigned)(unsigned short)l3 << 16);
    *(uint2*)(xh + (size_t)node * 128 + sub * 4) = hp;
    *(uint2*)(xl + (size_t)node * 128 + sub * 4) = lp;
  }
}

// ---------------- fused dense GEMM pair: h2 = (elu(aggX@W_in+b)) @ W_out ------

__global__ __launch_bounds__(256) void k_gemm12(const short* __restrict__ aggXh,
                                                const short* __restrict__ aggXl,
                                                const short* __restrict__ winth,
                                                const short* __restrict__ wintl,
                                                const float* __restrict__ b,
                                                const short* __restrict__ woutth,
                                                const short* __restrict__ wouttl,
                                                float* __restrict__ h2) {
  __shared__ short Xh[32 * 136];
  __shared__ short Xl[32 * 136];
  __shared__ short Yh[32 * 264];
  __shared__ short Yl[32 * 264];
  int t = threadIdx.x;
  int n0 = blockIdx.x * 32;
#pragma unroll
  for (int j = 0; j < 2; j++) {
    int i = t + 256 * j;
    int row = i >> 4, q = i & 15;
    int node = n0 + row; if (node >= NN) node = NN - 1;
    *(uint4*)&Xh[row * 136 + q * 8] = *(const uint4*)(aggXh + (size_t)node * 128 + q * 8);
    *(uint4*)&Xl[row * 136 + q * 8] = *(const uint4*)(aggXl + (size_t)node * 128 + q * 8);
  }
  __syncthreads();

  int w = t >> 6, lane = t & 63;
  int quad = lane >> 4, l16 = lane & 15;

  // ---- phase 1: x1 = elu(aggX @ W_in + b), wave owns 64 cols -> LDS Y ----
  {
    int nb = w * 64;
    int aoff0 = l16 * 136 + quad * 8;
    int aoff1 = (16 + l16) * 136 + quad * 8;

    f4_t acc[2][4];
#pragma unroll
    for (int mi = 0; mi < 2; mi++)
#pragma unroll
      for (int ni = 0; ni < 4; ni++) acc[mi][ni] = (f4_t){0.f, 0.f, 0.f, 0.f};

#pragma unroll
    for (int kb = 0; kb < 4; kb++) {
      int k0 = kb * 32;
      s8_t ah0 = *(const s8_t*)&Xh[aoff0 + k0];
      s8_t ah1 = *(const s8_t*)&Xh[aoff1 + k0];
      s8_t al0 = *(const s8_t*)&Xl[aoff0 + k0];
      s8_t al1 = *(const s8_t*)&Xl[aoff1 + k0];
#pragma unroll
      for (int ni = 0; ni < 4; ni++) {
        int bo = (nb + ni * 16 + l16) * 128 + quad * 8 + k0;
        s8_t bh = *(const s8_t*)(winth + bo);
        s8_t bl = *(const s8_t*)(wintl + bo);
        acc[0][ni] = __builtin_amdgcn_mfma_f32_16x16x32_bf16(ah0, bh, acc[0][ni], 0, 0, 0);
        acc[0][ni] = __builtin_amdgcn_mfma_f32_16x16x32_bf16(ah0, bl, acc[0][ni], 0, 0, 0);
        acc[0][ni] = __builtin_amdgcn_mfma_f32_16x16x32_bf16(al0, bh, acc[0][ni], 0, 0, 0);
        acc[1][ni] = __builtin_amdgcn_mfma_f32_16x16x32_bf16(ah1, bh, acc[1][ni], 0, 0, 0);
        acc[1][ni] = __builtin_amdgcn_mfma_f32_16x16x32_bf16(ah1, bl, acc[1][ni], 0, 0, 0);
        acc[1][ni] = __builtin_amdgcn_mfma_f32_16x16x32_bf16(al1, bh, acc[1][ni], 0, 0, 0);
      }
    }

#pragma unroll
    for (int mi = 0; mi < 2; mi++)
#pragma unroll
      for (int ni = 0; ni < 4; ni++) {
        int col = nb + ni * 16 + l16;
        float bv = b[col];
#pragma unroll
        for (int r = 0; r < 4; r++) {
          int row = mi * 16 + quad * 4 + r;
          float v = acc[mi][ni][r] + bv;
          v = v > 0.f ? v : expm1f(v);
          short hh, ll; split2(v, hh, ll);
          Yh[row * 264 + col] = hh;
          Yl[row * 264 + col] = ll;
        }
      }
  }
  __syncthreads();

  // ---- phase 2: h2 = x1 @ W_out, wave owns 32 cols ----
  {
    int nb = w * 32;
    int aoff0 = l16 * 264 + quad * 8;
    int aoff1 = (16 + l16) * 264 + quad * 8;

    f4_t acc[2][2];
#pragma unroll
    for (int mi = 0; mi < 2; mi++)
#pragma unroll
      for (int ni = 0; ni < 2; ni++) acc[mi][ni] = (f4_t){0.f, 0.f, 0.f, 0.f};

#pragma unroll
    for (int kb = 0; kb < 8; kb++) {
      int k0 = kb * 32;
      s8_t ah0 = *(const s8_t*)&Yh[aoff0 + k0];
      s8_t ah1 = *(const s8_t*)&Yh[aoff1 + k0];
      s8_t al0 = *(const s8_t*)&Yl[aoff0 + k0];
      s8_t al1 = *(const s8_t*)&Yl[aoff1 + k0];
#pragma unroll
      for (int ni = 0; ni < 2; ni++) {
        int bo = (nb + ni * 16 + l16) * 256 + quad * 8 + k0;
        s8_t bh = *(const s8_t*)(woutth + bo);
        s8_t bl = *(const s8_t*)(wouttl + bo);
        acc[0][ni] = __builtin_amdgcn_mfma_f32_16x16x32_bf16(ah0, bh, acc[0][ni], 0, 0, 0);
        acc[0][ni] = __builtin_amdgcn_mfma_f32_16x16x32_bf16(ah0, bl, acc[0][ni], 0, 0, 0);
        acc[0][ni] = __builtin_amdgcn_mfma_f32_16x16x32_bf16(al0, bh, acc[0][ni], 0, 0, 0);
        acc[1][ni] = __builtin_amdgcn_mfma_f32_16x16x32_bf16(ah1, bh, acc[1][ni], 0, 0, 0);
        acc[1][ni] = __builtin_amdgcn_mfma_f32_16x16x32_bf16(ah1, bl, acc[1][ni], 0, 0, 0);
        acc[1][ni] = __builtin_amdgcn_mfma_f32_16x16x32_bf16(al1, bh, acc[1][ni], 0, 0, 0);
      }
    }

#pragma unroll
    for (int mi = 0; mi < 2; mi++)
#pragma unroll
      for (int ni = 0; ni < 2; ni++) {
        int col = nb + ni * 16 + l16;
#pragma unroll
        for (int r = 0; r < 4; r++) {
          int node = n0 + mi * 16 + quad * 4 + r;
          if (node < NN) h2[(size_t)node * 128 + col] = acc[mi][ni][r];
        }
      }
  }
}

// ---------------- node-level decoder-layer1 factorization ----------------

__global__ __launch_bounds__(256) void k_pab(const short* __restrict__ x2h,
                                             const short* __restrict__ x2l,
                                             const short* __restrict__ w1th,
                                             const short* __restrict__ w1tl,
                                             const float* __restrict__ b1,
                                             float* __restrict__ Pa,
                                             float* __restrict__ Pb) {
  __shared__ short Xh[32 * 136];
  __shared__ short Xl[32 * 136];
  int t = threadIdx.x;
  int n0 = blockIdx.x * 32;
#pragma unroll
  for (int j = 0; j < 2; j++) {
    int i = t + 256 * j;
    int row = i >> 4, q = i & 15;
    int node = n0 + row; if (node >= NN) node = NN - 1;
    *(uint4*)&Xh[row * 136 + q * 8] = *(const uint4*)(x2h + (size_t)node * 128 + q * 8);
    *(uint4*)&Xl[row * 136 + q * 8] = *(const uint4*)(x2l + (size_t)node * 128 + q * 8);
  }
  __syncthreads();

  int w = t >> 6, lane = t & 63;
  int quad = lane >> 4, l16 = lane & 15;
  int nb = w * 32;
  int aoff0 = l16 * 136 + quad * 8;
  int aoff1 = (16 + l16) * 136 + quad * 8;
  int bo0 = (nb + l16) * 256 + quad * 8;
  int bo1 = (nb + 16 + l16) * 256 + quad * 8;

  f4_t aa[2][2], ab[2][2];
#pragma unroll
  for (int mi = 0; mi < 2; mi++)
#pragma unroll
    for (int ni = 0; ni < 2; ni++) {
      aa[mi][ni] = (f4_t){0.f, 0.f, 0.f, 0.f};
      ab[mi][ni] = (f4_t){0.f, 0.f, 0.f, 0.f};
    }

#pragma unroll
  for (int kb = 0; kb < 4; kb++) {
    int k0 = kb * 32;
    s8_t ah0 = *(const s8_t*)&Xh[aoff0 + k0];
    s8_t ah1 = *(const s8_t*)&Xh[aoff1 + k0];
    s8_t al0 = *(const s8_t*)&Xl[aoff0 + k0];
    s8_t al1 = *(const s8_t*)&Xl[aoff1 + k0];
    {
      s8_t bh0 = *(const s8_t*)(w1th + bo0 + k0);
      s8_t bh1 = *(const s8_t*)(w1th + bo1 + k0);
      s8_t bl0 = *(const s8_t*)(w1tl + bo0 + k0);
      s8_t bl1 = *(const s8_t*)(w1tl + bo1 + k0);
      aa[0][0] = __builtin_amdgcn_mfma_f32_16x16x32_bf16(ah0, bh0, aa[0][0], 0, 0, 0);
      aa[0][0] = __builtin_amdgcn_mfma_f32_16x16x32_bf16(ah0, bl0, aa[0][0], 0, 0, 0);
      aa[0][0] = __builtin_amdgcn_mfma_f32_16x16x32_bf16(al0, bh0, aa[0][0], 0, 0, 0);
      aa[0][1] = __builtin_amdgcn_mfma_f32_16x16x32_bf16(ah0, bh1, aa[0][1], 0, 0, 0);
      aa[0][1] = __builtin_amdgcn_mfma_f32_16x16x32_bf16(ah0, bl1, aa[0][1], 0, 0, 0);
      aa[0][1] = __builtin_amdgcn_mfma_f32_16x16x32_bf16(al0, bh1, aa[0][1], 0, 0, 0);
      aa[1][0] = __builtin_amdgcn_mfma_f32_16x16x32_bf16(ah1, bh0, aa[1][0], 0, 0, 0);
      aa[1][0] = __builtin_amdgcn_mfma_f32_16x16x32_bf16(ah1, bl0, aa[1][0], 0, 0, 0);
      aa[1][0] = __builtin_amdgcn_mfma_f32_16x16x32_bf16(al1, bh0, aa[1][0], 0, 0, 0);
      aa[1][1] = __builtin_amdgcn_mfma_f32_16x16x32_bf16(ah1, bh1, aa[1][1], 0, 0, 0);
      aa[1][1] = __builtin_amdgcn_mfma_f32_16x16x32_bf16(ah1, bl1, aa[1][1], 0, 0, 0);
      aa[1][1] = __builtin_amdgcn_mfma_f32_16x16x32_bf16(al1, bh1, aa[1][1], 0, 0, 0);
    }
    {
      s8_t bh0 = *(const s8_t*)(w1th + bo0 + 128 + k0);
      s8_t bh1 = *(const s8_t*)(w1th + bo1 + 128 + k0);
      s8_t bl0 = *(const s8_t*)(w1tl + bo0 + 128 + k0);
      s8_t bl1 = *(const s8_t*)(w1tl + bo1 + 128 + k0);
      ab[0][0] = __builtin_amdgcn_mfma_f32_16x16x32_bf16(ah0, bh0, ab[0][0], 0, 0, 0);
      ab[0][0] = __builtin_amdgcn_mfma_f32_16x16x32_bf16(ah0, bl0, ab[0][0], 0, 0, 0);
      ab[0][0] = __builtin_amdgcn_mfma_f32_16x16x32_bf16(al0, bh0, ab[0][0], 0, 0, 0);
      ab[0][1] = __builtin_amdgcn_mfma_f32_16x16x32_bf16(ah0, bh1, ab[0][1], 0, 0, 0);
      ab[0][1] = __builtin_amdgcn_mfma_f32_16x16x32_bf16(ah0, bl1, ab[0][1], 0, 0, 0);
      ab[0][1] = __builtin_amdgcn_mfma_f32_16x16x32_bf16(al0, bh1, ab[0][1], 0, 0, 0);
      ab[1][0] = __builtin_amdgcn_mfma_f32_16x16x32_bf16(ah1, bh0, ab[1][0], 0, 0, 0);
      ab[1][0] = __builtin_amdgcn_mfma_f32_16x16x32_bf16(ah1, bl0, ab[1][0], 0, 0, 0);
      ab[1][0] = __builtin_amdgcn_mfma_f32_16x16x32_bf16(al1, bh0, ab[1][0], 0, 0, 0);
      ab[1][1] = __builtin_amdgcn_mfma_f32_16x16x32_bf16(ah1, bh1, ab[1][1], 0, 0, 0);
      ab[1][1] = __builtin_amdgcn_mfma_f32_16x16x32_bf16(ah1, bl1, ab[1][1], 0, 0, 0);
      ab[1][1] = __builtin_amdgcn_mfma_f32_16x16x32_bf16(al1, bh1, ab[1][1], 0, 0, 0);
    }
  }

  float b1v0 = b1[nb + l16], b1v1 = b1[nb + 16 + l16];
#pragma unroll
  for (int mi = 0; mi < 2; mi++)
#pragma unroll
    for (int ni = 0; ni < 2; ni++) {
      int col = nb + ni * 16 + l16;
      float bv = ni ? b1v1 : b1v0;
#pragma unroll
      for (int r = 0; r < 4; r++) {
        int node = n0 + mi * 16 + quad * 4 + r;
        if (node < NN) {
          Pa[(size_t)node * 128 + col] = aa[mi][ni][r];
          Pb[(size_t)node * 128 + col] = ab[mi][ni][r] + bv;
        }
      }
    }
}

// ---------------- fused edge decoder v9 (src/dst unpacked from c1pack.x) ------

#define ST 136   // t1 LDS stride (shorts)

__global__ __launch_bounds__(256, 4) void k_decoder(
    const float* __restrict__ Pa, const float* __restrict__ Pb,
    const int4* __restrict__ c1pack,
    const short* __restrict__ w2th, const short* __restrict__ w2tl,
    const float* __restrict__ b2,
    const float* __restrict__ W3, const float* __restrict__ b3,
    float* __restrict__ out) {
  __shared__ short Th[32 * ST];
  __shared__ short Tl[32 * ST];
  __shared__ float part[4][32];

  int t = threadIdx.x;
  int b = blockIdx.x;
  int id = (b & 7) * 3125 + (b >> 3);   // XCD-contiguous CSR ranges
  int s0base = id * 32;

  {
    int le0 = t >> 4, q = t & 15;
    int4 p0 = c1pack[s0base + le0];
    int4 p1 = c1pack[s0base + le0 + 16];
    unsigned u0 = (unsigned)p0.x, u1 = (unsigned)p1.x;
    const float* pa0 = Pa + (size_t)(u0 & 0xffffu) * 128 + q * 8;
    const float* pb0 = Pb + (size_t)(u0 >> 16) * 128 + q * 8;
    const float* pa1 = Pa + (size_t)(u1 & 0xffffu) * 128 + q * 8;
    const float* pb1 = Pb + (size_t)(u1 >> 16) * 128 + q * 8;
    float4 ra0 = *(const float4*)(pa0);
    float4 ra1 = *(const float4*)(pa0 + 4);
    float4 rb0 = *(const float4*)(pb0);
    float4 rb1 = *(const float4*)(pb0 + 4);
    float4 ra2 = *(const float4*)(pa1);
    float4 ra3 = *(const float4*)(pa1 + 4);
    float4 rb2 = *(const float4*)(pb1);
    float4 rb3 = *(const float4*)(pb1 + 4);

    float v0[8], v1[8];
    v0[0] = ra0.x + rb0.x; v0[1] = ra0.y + rb0.y;
    v0[2] = ra0.z + rb0.z; v0[3] = ra0.w + rb0.w;
    v0[4] = ra1.x + rb1.x; v0[5] = ra1.y + rb1.y;
    v0[6] = ra1.z + rb1.z; v0[7] = ra1.w + rb1.w;
    v1[0] = ra2.x + rb2.x; v1[1] = ra2.y + rb2.y;
    v1[2] = ra2.z + rb2.z; v1[3] = ra2.w + rb2.w;
    v1[4] = ra3.x + rb3.x; v1[5] = ra3.y + rb3.y;
    v1[6] = ra3.z + rb3.z; v1[7] = ra3.w + rb3.w;

    s8_t hv0, lv0, hv1, lv1;
#pragma unroll
    for (int k = 0; k < 8; k++) {
      float x0 = fmaxf(v0[k], 0.f);
      float x1 = fmaxf(v1[k], 0.f);
      short hh, ll;
      split2(x0, hh, ll); hv0[k] = hh; lv0[k] = ll;
      split2(x1, hh, ll); hv1[k] = hh; lv1[k] = ll;
    }
    *(s8_t*)&Th[le0 * ST + q * 8] = hv0;
    *(s8_t*)&Tl[le0 * ST + q * 8] = lv0;
    *(s8_t*)&Th[(le0 + 16) * ST + q * 8] = hv1;
    *(s8_t*)&Tl[(le0 + 16) * ST + q * 8] = lv1;
  }
  __syncthreads();

  int w = t >> 6, lane = t & 63;
  int quad = lane >> 4, l16 = lane & 15;
  int nb = w * 32;
  float b2v0 = b2[nb + l16], b2v1 = b2[nb + 16 + l16];
  float w3a = W3[nb + l16], w3b = W3[nb + 16 + l16];

  int toff0 = l16 * ST + quad * 8;
  int toff1 = (16 + l16) * ST + quad * 8;
  int coff0 = (nb + l16) * 128 + quad * 8;
  int coff1 = (nb + 16 + l16) * 128 + quad * 8;

  f4_t acc2[2][2];
#pragma unroll
  for (int mi = 0; mi < 2; mi++)
#pragma unroll
    for (int ni = 0; ni < 2; ni++) acc2[mi][ni] = (f4_t){0.f, 0.f, 0.f, 0.f};

#pragma unroll
  for (int kb = 0; kb < 4; kb++) {
    int k0 = kb * 32;
    s8_t ah0 = *(const s8_t*)&Th[toff0 + k0];
    s8_t ah1 = *(const s8_t*)&Th[toff1 + k0];
    s8_t al0 = *(const s8_t*)&Tl[toff0 + k0];
    s8_t al1 = *(const s8_t*)&Tl[toff1 + k0];
    s8_t bh0 = *(const s8_t*)(w2th + coff0 + k0);
    s8_t bh1 = *(const s8_t*)(w2th + coff1 + k0);
    s8_t bl0 = *(const s8_t*)(w2tl + coff0 + k0);
    s8_t bl1 = *(const s8_t*)(w2tl + coff1 + k0);
    acc2[0][0] = __builtin_amdgcn_mfma_f32_16x16x32_bf16(ah0, bh0, acc2[0][0], 0, 0, 0);
    acc2[0][0] = __builtin_amdgcn_mfma_f32_16x16x32_bf16(ah0, bl0, acc2[0][0], 0, 0, 0);
    acc2[0][0] = __builtin_amdgcn_mfma_f32_16x16x32_bf16(al0, bh0, acc2[0][0], 0, 0, 0);
    acc2[0][1] = __builtin_amdgcn_mfma_f32_16x16x32_bf16(ah0, bh1, acc2[0][1], 0, 0, 0);
    acc2[0][1] = __builtin_amdgcn_mfma_f32_16x16x32_bf16(ah0, bl1, acc2[0][1], 0, 0, 0);
    acc2[0][1] = __builtin_amdgcn_mfma_f32_16x16x32_bf16(al0, bh1, acc2[0][1], 0, 0, 0);
    acc2[1][0] = __builtin_amdgcn_mfma_f32_16x16x32_bf16(ah1, bh0, acc2[1][0], 0, 0, 0);
    acc2[1][0] = __builtin_amdgcn_mfma_f32_16x16x32_bf16(ah1, bl0, acc2[1][0], 0, 0, 0);
    acc2[1][0] = __builtin_amdgcn_mfma_f32_16x16x32_bf16(al1, bh0, acc2[1][0], 0, 0, 0);
    acc2[1][1] = __builtin_amdgcn_mfma_f32_16x16x32_bf16(ah1, bh1, acc2[1][1], 0, 0, 0);
    acc2[1][1] = __builtin_amdgcn_mfma_f32_16x16x32_bf16(ah1, bl1, acc2[1][1], 0, 0, 0);
    acc2[1][1] = __builtin_amdgcn_mfma_f32_16x16x32_bf16(al1, bh1, acc2[1][1], 0, 0, 0);
  }

#pragma unroll
  for (int mi = 0; mi < 2; mi++) {
#pragma unroll
    for (int r = 0; r < 4; r++) {
      float pv = fmaxf(acc2[mi][0][r] + b2v0, 0.f) * w3a +
                 fmaxf(acc2[mi][1][r] + b2v1, 0.f) * w3b;
      pv += __shfl_xor(pv, 1);
      pv += __shfl_xor(pv, 2);
      pv += __shfl_xor(pv, 4);
      pv += __shfl_xor(pv, 8);
      if (l16 == 0) part[w][mi * 16 + quad * 4 + r] = pv;
    }
  }
  __syncthreads();

  if (t < 32) {
    float s = part[0][t] + part[1][t] + part[2][t] + part[3][t] + b3[0];
    int4 p = c1pack[s0base + t];
    out[p.z] = s;
  }
}

// ---------------- launch ----------------

extern "C" void kernel_launch(void* const* d_in, const int* in_sizes, int n_in,
                              void* d_out, int out_size, void* d_ws, size_t ws_size,
                              hipStream_t stream) {
  const int*   node_ids = (const int*)d_in[0];
  const int*   ei       = (const int*)d_in[1];
  const int*   nei      = (const int*)d_in[2];
  const float* eattr    = (const float*)d_in[3];
  const float* emb      = (const float*)d_in[4];
  const float* W_in     = (const float*)d_in[5];
  const float* b_in     = (const float*)d_in[6];
  const float* W_out    = (const float*)d_in[7];
  const float* b_out    = (const float*)d_in[8];
  const float* W1       = (const float*)d_in[9];
  const float* b1       = (const float*)d_in[10];
  const float* W2       = (const float*)d_in[11];
  const float* b2       = (const float*)d_in[12];
  const float* W3       = (const float*)d_in[13];
  const float* b3       = (const float*)d_in[14];
  float* out = (float*)d_out;

  // workspace layout (floats)
  float* ws    = (float*)d_ws;
  float* bufA  = ws;                          // N*128 f: aggXh/l -> Pa
  float* bufB  = bufA + (size_t)NN * 128;     // N*256 f: [h2 -> Pb | x2h/x2l]
  int*   cnt1  = (int*)(bufB + (size_t)NN * 256);
  int*   cnt2  = cnt1 + NN;
  float* deg1  = (float*)(cnt2 + NN);
  float* dinv1 = deg1 + NN;
  float* dinv2 = dinv1 + NN;
  int*   off1  = (int*)(dinv2 + NN);          // N+1
  int*   pos1  = off1 + NN + 1;               // N
  int*   off2  = pos1 + NN;                   // N+1
  int*   pos2  = off2 + NN + 1;               // N
  int4*  c1pack = (int4*)((((uintptr_t)(pos2 + NN)) + 15) & ~(uintptr_t)15);  // E
  int2*  c2pack = (int2*)(c1pack + NE);                                       // E
  short* w1th   = (short*)(c2pack + NE);
  short* w1tl   = w1th + 32768;
  short* w2th   = w1tl + 32768;
  short* w2tl   = w2th + 16384;
  short* winth  = w2tl + 16384;
  short* wintl  = winth + 32768;
  short* woutth = wintl + 32768;
  short* wouttl = woutth + 32768;
  int*   part   = (int*)(wouttl + 32768);     // 2*NCHUNK

  short* aggXh = (short*)bufA;                // N*128 shorts
  short* aggXl = aggXh + (size_t)NN * 128;
  float* Pa    = bufA;                        // overwrites aggX (dead after gemm12)
  float* h2    = bufB;                        // first half of bufB
  float* Pb    = bufB;                        // overwrites h2 (dead after agg2)
  short* x2h   = (short*)(bufB + (size_t)NN * 128);  // second half of bufB
  short* x2l   = x2h + (size_t)NN * 128;

  // weight split (W1, W2, W_in^T, W_out^T)
  k_wcvt<<<448, 256, 0, stream>>>(W1, W2, W_in, W_out,
                                  w1th, w1tl, w2th, w2tl,
                                  winth, wintl, woutth, wouttl);

  // CSR build: hist -> scan(3-phase, dinv fused) -> fill
  hipMemsetAsync(cnt1, 0, 3 * (size_t)NN * sizeof(int), stream);  // cnt1,cnt2,deg1
  k_hist<<<NE / 256, 256, 0, stream>>>(ei, nei, eattr, cnt1, deg1, cnt2);
  k_scan_part<<<2 * NCHUNK, 256, 0, stream>>>(cnt1, cnt2, deg1, dinv1, dinv2, part);
  k_scan_mid<<<1, 256, 0, stream>>>(part, off1 + NN, off2 + NN);
  k_scan_final<<<2 * NCHUNK, 256, 0, stream>>>(cnt1, cnt2, part,
                                               off1, pos1, off2, pos2);
  k_fill<<<NE / 256, 256, 0, stream>>>(ei, nei, eattr, node_ids, dinv1, dinv2,
                                       pos1, c1pack, pos2, c2pack);

  // layer 1: aggregate (emb row pre-resolved) -> fused GEMM1+GEMM2
  k_agg1<<<NN / 4, 256, 0, stream>>>(off1, c1pack, emb, aggXh, aggXl);
  k_gemm12<<<(NN + 31) / 32, 256, 0, stream>>>(aggXh, aggXl, winth, wintl, b_in,
                                               woutth, wouttl, h2);

  // layer 2: aggregate h2 (+bias+ELU+split fused) -> x2
  k_agg2<<<NN / 4, 256, 0, stream>>>(off2, c2pack, h2, b_out, x2h, x2l);

  // decoder layer-1 factorization: Pa/Pb per node (b1 folded into Pb)
  k_pab<<<(NN + 31) / 32, 256, 0, stream>>>(x2h, x2l, w1th, w1tl, b1, Pa, Pb);

  // decoder v9 (src/dst unpacked from packed field)
  k_decoder<<<NE / 32, 256, 0, stream>>>(Pa, Pb, c1pack,
                                         w2th, w2tl, b2, W3, b3, out);
}